// Round 11
// baseline (321.995 us; speedup 1.0000x reference)
//
#include <hip/hip_runtime.h>

// ---------------------------------------------------------------------------
// GIN 3-layer forward on MI355X (gfx950).
//   - features/weights bf16 (f32 accumulate); feature tables stored
//     SLICE-MAJOR: x_s[slice][node][16 cols] (8 slices x 32B). The segment-
//     sum gather runs slice = blockIdx&7 -> one slice per XCD (round-robin
//     dispatch) -> per-XCD working set 3.2MB < 4MB L2 -> gather at L2 speed
//     (R10: node-major gather = 50% L2 miss, 62us at 3.5TB/s fabric).
//   - CSR build: LDS-binned scatter with FULL-LINE flushes (sentinel-padded
//     64B bursts; this chip's L2 does NOT merge scattered partial-line
//     stores), bscan, per-bucket build.
//   - k_mlp: MFMA 16x16x32 bf16, BM=128, 4 waves, LDS = z/h tile only
//     (34.8 KB); B-fragments from global (L2-resident).
//   - layer 1 only on active set = roots U in-neighbors(roots)
//   - layer 2 only at the 1024 roots
//   NOTE: edge packing assumes N <= 2^17; bins assume N <= 100352.
// ---------------------------------------------------------------------------

typedef __bf16  bf16x8 __attribute__((ext_vector_type(8)));
typedef float   f32x4  __attribute__((ext_vector_type(4)));

#define NBINS 784     // >= (N+127)/128
#define BCAP  38      // words per LDS bin (per-bin lambda ~8)
#define CAP   8192    // words per global bucket cell (real ~2048 + pads)
#define LDR   136     // MLP LDS row stride in shorts (+8 pad)

// ---------------- conversion: f32 node-major -> bf16 slice-major ----------
// out[((s*N + node)*2 + half)*8 + q] = bf16(x[node*128 + s*16 + half*8 + q])
__global__ __launch_bounds__(256) void k_cvt_x(const float4* __restrict__ in,
                                               unsigned short* __restrict__ outb,
                                               int N) {
    int i = blockIdx.x * 256 + threadIdx.x;   // N*16 total
    if (i >= N * 16) return;
    int s    = i / (2 * N);
    int rem  = i - s * 2 * N;
    int node = rem >> 1;
    int half = rem & 1;
    const float4* pa = &in[(size_t)node * 32 + s * 4 + half * 2];
    float4 a = pa[0], b = pa[1];
    bf16x8 v;
    v[0] = (__bf16)a.x; v[1] = (__bf16)a.y; v[2] = (__bf16)a.z; v[3] = (__bf16)a.w;
    v[4] = (__bf16)b.x; v[5] = (__bf16)b.y; v[6] = (__bf16)b.z; v[7] = (__bf16)b.w;
    *(bf16x8*)&outb[(size_t)i * 8] = v;
}

// 4 weight matrices -> transposed bf16, contiguous output (4 x 128 x 128)
__global__ __launch_bounds__(256) void k_cvt_w4(const float* __restrict__ wa,
                                                const float* __restrict__ wb,
                                                const float* __restrict__ wc,
                                                const float* __restrict__ wd,
                                                unsigned short* __restrict__ out) {
    int i = blockIdx.x * 256 + threadIdx.x;    // 65536
    int m = i >> 14, j = i & 16383;
    const float* w = (m == 0) ? wa : (m == 1) ? wb : (m == 2) ? wc : wd;
    int k = j >> 7, n = j & 127;
    *(__bf16*)&out[m * 16384 + n * 128 + k] = (__bf16)w[j];
}

// ---------------- LDS-binned scatter with full-line flush ----------------
__global__ __launch_bounds__(256) void k_scatter(const int* __restrict__ src,
                                                 const int* __restrict__ dst,
                                                 int* __restrict__ gcnt,     // NB*16 padded
                                                 int* __restrict__ realcnt,  // NB
                                                 unsigned* __restrict__ ebuf,
                                                 int e, int nb) {
    __shared__ unsigned lbuf[NBINS * BCAP];   // 119.2 KB
    __shared__ int lcnt[NBINS];
    __shared__ int sbase[NBINS];
    const int t = threadIdx.x;
    for (int b = t; b < nb; b += 256) lcnt[b] = 0;
    __syncthreads();

    const int per = (((e + 255) / 256) + 7) & ~7;   // 8-aligned slice
    const int beg = blockIdx.x * per;
    const int end = (beg + per < e) ? beg + per : e;

    for (int base = beg; base < end; base += 2048) {
        int i0 = base + t * 8;
        if (i0 >= end) continue;
        if (i0 + 8 <= end) {
            int4 s0 = *(const int4*)&src[i0];
            int4 s1 = *(const int4*)&src[i0 + 4];
            int4 d0 = *(const int4*)&dst[i0];
            int4 d1 = *(const int4*)&dst[i0 + 4];
            int ss[8] = {s0.x, s0.y, s0.z, s0.w, s1.x, s1.y, s1.z, s1.w};
            int dd[8] = {d0.x, d0.y, d0.z, d0.w, d1.x, d1.y, d1.z, d1.w};
#pragma unroll
            for (int q = 0; q < 8; ++q) {
                int b = dd[q] >> 7;
                int p = atomicAdd(&lcnt[b], 1);
                if (p < BCAP)
                    lbuf[b * BCAP + p] =
                        (unsigned)ss[q] | ((unsigned)(dd[q] & 127) << 17);
            }
        } else {
            int lim = (i0 + 8 < end) ? i0 + 8 : end;
            for (int i = i0; i < lim; ++i) {
                int d = dst[i];
                int b = d >> 7;
                int p = atomicAdd(&lcnt[b], 1);
                if (p < BCAP)
                    lbuf[b * BCAP + p] =
                        (unsigned)src[i] | ((unsigned)(d & 127) << 17);
            }
        }
    }
    __syncthreads();

    // phase 1: reserve cell ranges
    for (int b = t; b < nb; b += 256) {
        int r = lcnt[b]; if (r > BCAP) r = BCAP;
        int bb = 0;
        if (r > 0) {
            int nf = (r + 15) & ~15;
            bb = atomicAdd(&gcnt[b * 16], nf);
            atomicAdd(&realcnt[b], r);
        }
        sbase[b] = bb;
    }
    __syncthreads();

    // phase 2: cooperative full-line copies (16-lane group per bin)
    const int wave = t >> 6, lane = t & 63;
    const int gidx = wave * 4 + (lane >> 4), sub = lane & 15;
    for (int b = gidx; b < nb; b += 16) {
        int r = lcnt[b]; if (r > BCAP) r = BCAP;
        if (r == 0) continue;
        int nf = (r + 15) & ~15;
        int base2 = sbase[b];
        unsigned* cell = ebuf + (size_t)b * CAP;
        for (int j = sub; j < nf; j += 16) {
            unsigned v = (j < r) ? lbuf[b * BCAP + j] : 0xFFFFFFFFu;
            if (base2 + j < CAP) cell[base2 + j] = v;
        }
    }
}

// one block: exclusive scan of nb real bucket counts (nb <= 1024); rp[n]=e
__global__ __launch_bounds__(1024) void k_bscan(const int* __restrict__ realcnt,
                                                int* __restrict__ boff,
                                                int* __restrict__ rp,
                                                int nb, int n, int e) {
    __shared__ int sh[1024];
    int t = threadIdx.x;
    sh[t] = (t < nb) ? realcnt[t] : 0;
    __syncthreads();
    for (int off = 1; off < 1024; off <<= 1) {
        int u = (t >= off) ? sh[t - off] : 0;
        __syncthreads();
        sh[t] += u;
        __syncthreads();
    }
    if (t < nb) boff[t] = (t == 0) ? 0 : sh[t - 1];
    if (t == 0) rp[n] = e;
}

// one block per bucket: histogram (skip sentinels) -> scan -> rp -> csr
__global__ __launch_bounds__(256) void k_build(const unsigned* __restrict__ ebuf,
                                               const int* __restrict__ gcnt,
                                               const int* __restrict__ boff,
                                               int* __restrict__ rp,
                                               int* __restrict__ csr, int n) {
    __shared__ int bins[128];
    __shared__ int incl[128];
    __shared__ int cur[128];
    int b = blockIdx.x, t = threadIdx.x;
    if (t < 128) bins[t] = 0;
    __syncthreads();
    int c = gcnt[b * 16]; if (c > CAP) c = CAP;
    const unsigned* seg = ebuf + ((size_t)b * CAP);
    for (int j = t; j < c; j += 256) {
        unsigned w = seg[j];
        if (w != 0xFFFFFFFFu) atomicAdd(&bins[(w >> 17) & 127], 1);
    }
    __syncthreads();
    if (t < 128) incl[t] = bins[t];
    __syncthreads();
    for (int off = 1; off < 128; off <<= 1) {
        int u = (t < 128 && t >= off) ? incl[t - off] : 0;
        __syncthreads();
        if (t < 128) incl[t] += u;
        __syncthreads();
    }
    int base = boff[b];
    if (t < 128) {
        int ex = (t == 0) ? 0 : incl[t - 1];
        cur[t] = ex;
        int node = b * 128 + t;
        if (node < n) rp[node] = base + ex;
    }
    __syncthreads();
    for (int j = t; j < c; j += 256) {
        unsigned w = seg[j];
        if (w != 0xFFFFFFFFu) {
            int slot = atomicAdd(&cur[(w >> 17) & 127], 1);
            csr[base + slot] = (int)(w & 0x1FFFF);
        }
    }
}

// ---------------- active set (roots + their in-neighbors) ----------------
__global__ void k_flag(const int* __restrict__ roots, int nr,
                       const int* __restrict__ rp, const int* __restrict__ csr,
                       int* __restrict__ af) {
    int i = blockIdx.x * blockDim.x + threadIdx.x;
    if (i >= nr) return;
    int r = roots[i];
    af[r] = 1;
    int e = rp[r + 1];
    for (int k = rp[r]; k < e; ++k) af[csr[k]] = 1;
}

__global__ void k_compact(const int* __restrict__ af, int* __restrict__ list,
                          int* __restrict__ cnt, int n) {
    int i = blockIdx.x * blockDim.x + threadIdx.x;
    if (i < n && af[i]) {
        int p = atomicAdd(cnt, 1);
        list[p] = i;
    }
}

// ---------------- segment sum + GIN update, slice-major ----------------
// z_s[s][j][*] = (1+eps)*x_s[s][node][*] + sum_{v in N(node)} x_s[s][v][*]
// block: slice = blockIdx&7 (one slice per XCD -> 3.2MB L2-resident table),
// 128 rows x 2 lanes; f32 accum, bf16 out. Full-line contiguous writes.
__global__ __launch_bounds__(256) void k_segz(const unsigned short* __restrict__ xs,
                                              int xstr,
                                              const int* __restrict__ rp,
                                              const int* __restrict__ csr,
                                              const float* __restrict__ epsp,
                                              unsigned short* __restrict__ zs,
                                              int zstr,
                                              const int* __restrict__ list,
                                              const int* __restrict__ cntp, int n) {
    const int s  = blockIdx.x & 7;
    const int rb = blockIdx.x >> 3;
    const int t  = threadIdx.x;
    int rows = n;
    if (cntp) { int c = *cntp; rows = c < n ? c : n; }
    int j = rb * 128 + (t >> 1);
    if (j >= rows) return;
    const int half = t & 1;
    int node = list ? list[j] : j;
    int b = rp[node], e = rp[node + 1];
    const unsigned short* xsl = xs + (size_t)s * xstr * 16 + half * 8;
    float s0[8], s1[8];
#pragma unroll
    for (int q = 0; q < 8; ++q) { s0[q] = 0.f; s1[q] = 0.f; }
    int k = b;
    for (; k + 1 < e; k += 2) {
        bf16x8 v0 = *(const bf16x8*)&xsl[(size_t)csr[k]     * 16];
        bf16x8 v1 = *(const bf16x8*)&xsl[(size_t)csr[k + 1] * 16];
#pragma unroll
        for (int q = 0; q < 8; ++q) { s0[q] += (float)v0[q]; s1[q] += (float)v1[q]; }
    }
    if (k < e) {
        bf16x8 v0 = *(const bf16x8*)&xsl[(size_t)csr[k] * 16];
#pragma unroll
        for (int q = 0; q < 8; ++q) s0[q] += (float)v0[q];
    }
    const float epsv = 1.0f + epsp[0];
    bf16x8 xv = *(const bf16x8*)&xsl[(size_t)node * 16];
    bf16x8 o;
#pragma unroll
    for (int q = 0; q < 8; ++q)
        o[q] = (__bf16)(epsv * (float)xv[q] + s0[q] + s1[q]);
    *(bf16x8*)&zs[(size_t)s * zstr * 16 + (size_t)j * 16 + half * 8] = o;
}

// ---------------- MLP: out = relu( relu(z@w1+b1) @ w2 + b2 ) ----------------
// z read slice-major (zstr), out written slice-major (outstr, by node id).
__global__ __launch_bounds__(256) void k_mlp(const unsigned short* __restrict__ zbuf,
                                             int zstr,
                                             const unsigned short* __restrict__ w1T,
                                             const float* __restrict__ b1,
                                             const unsigned short* __restrict__ w2T,
                                             const float* __restrict__ b2,
                                             unsigned short* __restrict__ out,
                                             int outstr,
                                             const int* __restrict__ list,
                                             const int* __restrict__ cntp, int nrows) {
    __shared__ unsigned short zt[128 * LDR];   // 34.8 KB
    const int t = threadIdx.x;
    int rows = nrows;
    if (cntp) { int c = *cntp; rows = c < nrows ? c : nrows; }
    const int row0 = blockIdx.x * 128;
    if (row0 >= rows) return;

    // stage z tile: 1024 chunks of 32B, i = r*8 + sl
    for (int i = t; i < 1024; i += 256) {
        int r = i >> 3, sl = i & 7;
        int g = row0 + r;
        bf16x8 zv0, zv1;
        if (g < rows) {
            const unsigned short* pz = &zbuf[(size_t)sl * zstr * 16 + (size_t)g * 16];
            zv0 = *(const bf16x8*)&pz[0];
            zv1 = *(const bf16x8*)&pz[8];
        } else {
#pragma unroll
            for (int q = 0; q < 8; ++q) { zv0[q] = (__bf16)0.0f; zv1[q] = (__bf16)0.0f; }
        }
        *(bf16x8*)&zt[r * LDR + sl * 16]     = zv0;
        *(bf16x8*)&zt[r * LDR + sl * 16 + 8] = zv1;
    }
    __syncthreads();

    const int lane = t & 63;
    const int wm = (t >> 7) & 1, wn = (t >> 6) & 1;
    const int lr = lane & 15, lk = lane >> 4;

    f32x4 zero4 = {0.f, 0.f, 0.f, 0.f};
    f32x4 acc[4][4];
#pragma unroll
    for (int mt = 0; mt < 4; ++mt)
#pragma unroll
        for (int nt = 0; nt < 4; ++nt) acc[mt][nt] = zero4;

    // -------- GEMM1: z @ w1 (B from global, L2-resident) --------
#pragma unroll
    for (int kb = 0; kb < 4; ++kb) {
        const int c = kb * 4 + lk;
        bf16x8 a[4];
#pragma unroll
        for (int mt = 0; mt < 4; ++mt)
            a[mt] = *(const bf16x8*)&zt[(wm * 64 + mt * 16 + lr) * LDR + c * 8];
#pragma unroll
        for (int nt = 0; nt < 4; ++nt) {
            bf16x8 b = *(const bf16x8*)&w1T[(wn * 64 + nt * 16 + lr) * 128 + c * 8];
#pragma unroll
            for (int mt = 0; mt < 4; ++mt)
                acc[mt][nt] = __builtin_amdgcn_mfma_f32_16x16x32_bf16(a[mt], b, acc[mt][nt], 0, 0, 0);
        }
    }
    __syncthreads();   // all zt reads done before in-place h overwrite

    // h = relu(acc + b1) -> zt (in place)
#pragma unroll
    for (int nt = 0; nt < 4; ++nt) {
        int col = wn * 64 + nt * 16 + lr;
        float bv = b1[col];
#pragma unroll
        for (int mt = 0; mt < 4; ++mt)
#pragma unroll
            for (int q = 0; q < 4; ++q) {
                int hr = wm * 64 + mt * 16 + lk * 4 + q;
                float hv = fmaxf(acc[mt][nt][q] + bv, 0.f);
                *(__bf16*)&zt[hr * LDR + col] = (__bf16)hv;
            }
    }
    __syncthreads();

    // -------- GEMM2: h @ w2 --------
    f32x4 acc2[4][4];
#pragma unroll
    for (int mt = 0; mt < 4; ++mt)
#pragma unroll
        for (int nt = 0; nt < 4; ++nt) acc2[mt][nt] = zero4;
#pragma unroll
    for (int kb = 0; kb < 4; ++kb) {
        const int c = kb * 4 + lk;
        bf16x8 a[4];
#pragma unroll
        for (int mt = 0; mt < 4; ++mt)
            a[mt] = *(const bf16x8*)&zt[(wm * 64 + mt * 16 + lr) * LDR + c * 8];
#pragma unroll
        for (int nt = 0; nt < 4; ++nt) {
            bf16x8 b = *(const bf16x8*)&w2T[(wn * 64 + nt * 16 + lr) * 128 + c * 8];
#pragma unroll
            for (int mt = 0; mt < 4; ++mt)
                acc2[mt][nt] = __builtin_amdgcn_mfma_f32_16x16x32_bf16(a[mt], b, acc2[mt][nt], 0, 0, 0);
        }
    }

    // out = relu(acc2 + b2), slice-major scalar stores
#pragma unroll
    for (int nt = 0; nt < 4; ++nt) {
        int col = wn * 64 + nt * 16 + lr;
        float bv = b2[col];
        int sl = col >> 4, cc = col & 15;
#pragma unroll
        for (int mt = 0; mt < 4; ++mt)
#pragma unroll
            for (int q = 0; q < 4; ++q) {
                int gr = row0 + wm * 64 + mt * 16 + lk * 4 + q;
                if (gr < rows) {
                    int node = list ? list[gr] : gr;
                    float ov = fmaxf(acc2[mt][nt][q] + bv, 0.f);
                    *(__bf16*)&out[(size_t)sl * outstr * 16 + (size_t)node * 16 + cc] = (__bf16)ov;
                }
            }
    }
}

// ---------------- layer 2 at roots only (x2 slice-major, stride N) --------
__global__ __launch_bounds__(128) void k_root(const unsigned short* __restrict__ x2,
                                              int xstr,
                                              const int* __restrict__ rp,
                                              const int* __restrict__ csr,
                                              const int* __restrict__ roots,
                                              const float* __restrict__ epsp,
                                              const float* __restrict__ wa,
                                              const float* __restrict__ ba,
                                              const float* __restrict__ wb,
                                              const float* __restrict__ bb,
                                              float* __restrict__ out) {
    __shared__ float hin[128];
    __shared__ float h[64];
    int r = blockIdx.x, t = threadIdx.x;
    int node = roots[r];
    const unsigned short* base = x2 + (size_t)(t >> 4) * xstr * 16 + (t & 15);
    float s = (1.0f + epsp[0]) * (float)(*(const __bf16*)&base[(size_t)node * 16]);
    int b = rp[node], e = rp[node + 1];
    for (int k = b; k < e; ++k)
        s += (float)(*(const __bf16*)&base[(size_t)csr[k] * 16]);
    hin[t] = s;
    __syncthreads();
    if (t < 64) {
        float a = ba[t];
        for (int k = 0; k < 128; ++k) a += hin[k] * wa[k * 64 + t];
        h[t] = fmaxf(a, 0.f);
    }
    __syncthreads();
    if (t < 64) {
        float a = bb[t];
        for (int k = 0; k < 64; ++k) a += h[k] * wb[k * 64 + t];
        out[(size_t)r * 64 + t] = a;
    }
}

extern "C" void kernel_launch(void* const* d_in, const int* in_sizes, int n_in,
                              void* d_out, int out_size, void* d_ws, size_t ws_size,
                              hipStream_t stream) {
    const float* x    = (const float*)d_in[0];
    const int*   ei   = (const int*)d_in[1];
    const int*   root = (const int*)d_in[2];
    const float* eps0 = (const float*)d_in[3];
    const float* w0a  = (const float*)d_in[4];
    const float* b0a  = (const float*)d_in[5];
    const float* w0b  = (const float*)d_in[6];
    const float* b0b  = (const float*)d_in[7];
    const float* eps1 = (const float*)d_in[8];
    const float* w1a  = (const float*)d_in[9];
    const float* b1a  = (const float*)d_in[10];
    const float* w1b  = (const float*)d_in[11];
    const float* b1b  = (const float*)d_in[12];
    const float* eps2 = (const float*)d_in[13];
    const float* w2a  = (const float*)d_in[14];
    const float* b2a  = (const float*)d_in[15];
    const float* w2b  = (const float*)d_in[16];
    const float* b2b  = (const float*)d_in[17];

    const int N  = in_sizes[0] / 128;
    const int E  = in_sizes[1] / 2;
    const int NR = in_sizes[2];
    const int MAXACT = 65536;
    const int NB = (N + 127) / 128;           // buckets of 128 nodes (782)
    const int* src = ei;
    const int* dst = ei + E;

    // ---- workspace layout ----
    char* p = (char*)d_ws;
    unsigned short* xb = (unsigned short*)p; p += (size_t)N * 128 * 2;        // 25.6 MB (slice-major)
    unsigned short* x1 = (unsigned short*)p; p += (size_t)N * 128 * 2;        // 25.6 MB (slice-major)
    unsigned short* z0 = (unsigned short*)p; p += (size_t)N * 128 * 2;        // 25.6 MB (slice-major)
    // shared region: ebuf (CSR build) then x2 (mlp1 output) — disjoint in time
    char* shared0 = p;
    size_t ebuf_bytes = (size_t)NB * CAP * 4;                                 // 25.6 MB
    size_t x2_bytes   = (size_t)N * 128 * 2;                                  // 25.6 MB
    p += (ebuf_bytes > x2_bytes ? ebuf_bytes : x2_bytes);
    unsigned*       ebuf = (unsigned*)shared0;
    unsigned short* x2   = (unsigned short*)shared0;                          // slice-major, stride N
    unsigned short* z1   = (unsigned short*)p; p += (size_t)MAXACT * 128 * 2; // 16.8 MB (slice-major, stride MAXACT)
    unsigned short* wT   = (unsigned short*)p; p += 4 * 128 * 128 * 2;
    int* rp      = (int*)p; p += (size_t)(N + 64) * 4;
    int* list    = (int*)p; p += (size_t)(N + 64) * 4;
    int* boff    = (int*)p; p += 4096;
    // zeroed region (single memset): af | cnt | gcnt | realcnt
    char* zbeg = p;
    int* af      = (int*)p; p += (size_t)(N + 64) * 4;
    int* cnt     = (int*)p; p += 256;
    int* gcnt    = (int*)p; p += (size_t)NB * 16 * 4;      // 64B-padded counters
    int* realcnt = (int*)p; p += (size_t)(NB + 64) * 4;
    size_t zbytes = (size_t)(p - zbeg);
    int* csr     = (int*)p; p += (size_t)E * 4;
    unsigned short* w0aT = wT;
    unsigned short* w0bT = wT + 16384;
    unsigned short* w1aT = wT + 32768;
    unsigned short* w1bT = wT + 49152;

    // ---- conversions ----
    k_cvt_x<<<(N * 16 + 255) / 256, 256, 0, stream>>>((const float4*)x, xb, N);
    k_cvt_w4<<<256, 256, 0, stream>>>(w0a, w0b, w1a, w1b, wT);

    // ---- CSR build ----
    hipMemsetAsync(zbeg, 0, zbytes, stream);
    k_scatter<<<256, 256, 0, stream>>>(src, dst, gcnt, realcnt, ebuf, E, NB);
    k_bscan<<<1, 1024, 0, stream>>>(realcnt, boff, rp, NB, N, E);
    k_build<<<NB, 256, 0, stream>>>(ebuf, gcnt, boff, rp, csr, N);

    // ---- active set ----
    k_flag<<<(NR + 255) / 256, 256, 0, stream>>>(root, NR, rp, csr, af);
    k_compact<<<(N + 255) / 256, 256, 0, stream>>>(af, list, cnt, N);

    // ---- layer 0 (all nodes) ----
    k_segz<<<8 * ((N + 127) / 128), 256, 0, stream>>>(xb, N, rp, csr, eps0,
                                                      z0, N, nullptr, nullptr, N);
    k_mlp<<<(N + 127) / 128, 256, 0, stream>>>(z0, N, w0aT, b0a, w0bT, b0b,
                                               x1, N, nullptr, nullptr, N);
    // ---- layer 1 (active set only) ----
    k_segz<<<8 * ((MAXACT + 127) / 128), 256, 0, stream>>>(x1, N, rp, csr, eps1,
                                                           z1, MAXACT, list, cnt, MAXACT);
    k_mlp<<<(MAXACT + 127) / 128, 256, 0, stream>>>(z1, MAXACT, w1aT, b1a, w1bT, b1b,
                                                    x2, N, list, cnt, MAXACT);
    // ---- layer 2 (roots only) ----
    k_root<<<NR, 128, 0, stream>>>(x2, N, rp, csr, root, eps2, w2a, b2a, w2b, b2b,
                                   (float*)d_out);
}

// Round 12
// 232.939 us; speedup vs baseline: 1.3823x; 1.3823x over previous
//
#include <hip/hip_runtime.h>

// ---------------------------------------------------------------------------
// GIN 3-layer forward on MI355X (gfx950).
//   - features/weights bf16 node-major (f32 accumulate). R11 lesson: slice-
//     major 32B granules halve line efficiency and XCD pinning via blockIdx
//     is unreliable -> node-major 256B rows restored (gather runs at ~6.6
//     TB/s logical, the practical ceiling).
//   - CSR build: LDS-binned scatter with FULL-LINE flushes (sentinel-padded
//     64B bursts; this chip's L2 does NOT merge scattered partial-line
//     stores). 512 threads/block (8 waves/CU) for the latency-bound binning.
//   - k_segz: segment-sum gather (16 lanes/node, bf16x8, f32 accum) fused
//     with GIN update z=(1+eps)x+sum. Standalone max-TLP kernel (R9 lesson).
//   - k_mlp: MFMA 16x16x32 bf16, BM=128, 4 waves, LDS = z/h tile only
//     (34.8 KB); B from global (L2-resident). Output routed through LDS ->
//     bf16x8 stores = full-line writes even for list-scattered rows.
//   - layer 1 only on active set = roots U in-neighbors(roots)
//   - layer 2 only at the 1024 roots
//   NOTE: edge packing assumes N <= 2^17; bins assume N <= 100352.
// ---------------------------------------------------------------------------

typedef __bf16  bf16x8 __attribute__((ext_vector_type(8)));
typedef float   f32x4  __attribute__((ext_vector_type(4)));

#define NBINS 784     // >= (N+127)/128
#define BCAP  38      // words per LDS bin (per-bin lambda ~8)
#define CAP   8192    // words per global bucket cell (real ~2048 + pads)
#define LDR   136     // MLP LDS row stride in shorts (+8 pad)

// ---------------- conversion kernels ----------------
__global__ __launch_bounds__(256) void k_cvt_x(const float4* __restrict__ in,
                                               unsigned short* __restrict__ outb,
                                               long n8) {
    long i = (long)blockIdx.x * 256 + threadIdx.x;
    if (i >= n8) return;
    float4 a = in[2 * i], b = in[2 * i + 1];
    bf16x8 v;
    v[0] = (__bf16)a.x; v[1] = (__bf16)a.y; v[2] = (__bf16)a.z; v[3] = (__bf16)a.w;
    v[4] = (__bf16)b.x; v[5] = (__bf16)b.y; v[6] = (__bf16)b.z; v[7] = (__bf16)b.w;
    *(bf16x8*)&outb[i * 8] = v;
}

// 4 weight matrices -> transposed bf16, contiguous output (4 x 128 x 128)
__global__ __launch_bounds__(256) void k_cvt_w4(const float* __restrict__ wa,
                                                const float* __restrict__ wb,
                                                const float* __restrict__ wc,
                                                const float* __restrict__ wd,
                                                unsigned short* __restrict__ out) {
    int i = blockIdx.x * 256 + threadIdx.x;    // 65536
    int m = i >> 14, j = i & 16383;
    const float* w = (m == 0) ? wa : (m == 1) ? wb : (m == 2) ? wc : wd;
    int k = j >> 7, n = j & 127;
    *(__bf16*)&out[m * 16384 + n * 128 + k] = (__bf16)w[j];
}

// ---------------- LDS-binned scatter with full-line flush ----------------
// 512 threads (8 waves/CU): binning is LDS-atomic latency bound, TLP helps.
__global__ __launch_bounds__(512) void k_scatter(const int* __restrict__ src,
                                                 const int* __restrict__ dst,
                                                 int* __restrict__ gcnt,     // NB*16 padded
                                                 int* __restrict__ realcnt,  // NB
                                                 unsigned* __restrict__ ebuf,
                                                 int e, int nb) {
    __shared__ unsigned lbuf[NBINS * BCAP];   // 119.2 KB
    __shared__ int lcnt[NBINS];
    __shared__ int sbase[NBINS];
    const int t = threadIdx.x;
    for (int b = t; b < nb; b += 512) lcnt[b] = 0;
    __syncthreads();

    const int per = (((e + 255) / 256) + 7) & ~7;   // 8-aligned slice, 256 blocks
    const int beg = blockIdx.x * per;
    const int end = (beg + per < e) ? beg + per : e;

    for (int base = beg; base < end; base += 4096) {
        int i0 = base + t * 8;
        if (i0 >= end) continue;
        if (i0 + 8 <= end) {
            int4 s0 = *(const int4*)&src[i0];
            int4 s1 = *(const int4*)&src[i0 + 4];
            int4 d0 = *(const int4*)&dst[i0];
            int4 d1 = *(const int4*)&dst[i0 + 4];
            int ss[8] = {s0.x, s0.y, s0.z, s0.w, s1.x, s1.y, s1.z, s1.w};
            int dd[8] = {d0.x, d0.y, d0.z, d0.w, d1.x, d1.y, d1.z, d1.w};
#pragma unroll
            for (int q = 0; q < 8; ++q) {
                int b = dd[q] >> 7;
                int p = atomicAdd(&lcnt[b], 1);
                if (p < BCAP)
                    lbuf[b * BCAP + p] =
                        (unsigned)ss[q] | ((unsigned)(dd[q] & 127) << 17);
            }
        } else {
            int lim = (i0 + 8 < end) ? i0 + 8 : end;
            for (int i = i0; i < lim; ++i) {
                int d = dst[i];
                int b = d >> 7;
                int p = atomicAdd(&lcnt[b], 1);
                if (p < BCAP)
                    lbuf[b * BCAP + p] =
                        (unsigned)src[i] | ((unsigned)(d & 127) << 17);
            }
        }
    }
    __syncthreads();

    // phase 1: reserve cell ranges
    for (int b = t; b < nb; b += 512) {
        int r = lcnt[b]; if (r > BCAP) r = BCAP;
        int bb = 0;
        if (r > 0) {
            int nf = (r + 15) & ~15;
            bb = atomicAdd(&gcnt[b * 16], nf);
            atomicAdd(&realcnt[b], r);
        }
        sbase[b] = bb;
    }
    __syncthreads();

    // phase 2: cooperative full-line copies (16-lane group per bin, 32 groups)
    const int wave = t >> 6, lane = t & 63;
    const int gidx = wave * 4 + (lane >> 4), sub = lane & 15;
    for (int b = gidx; b < nb; b += 32) {
        int r = lcnt[b]; if (r > BCAP) r = BCAP;
        if (r == 0) continue;
        int nf = (r + 15) & ~15;
        int base2 = sbase[b];
        unsigned* cell = ebuf + (size_t)b * CAP;
        for (int j = sub; j < nf; j += 16) {
            unsigned v = (j < r) ? lbuf[b * BCAP + j] : 0xFFFFFFFFu;
            if (base2 + j < CAP) cell[base2 + j] = v;
        }
    }
}

// one block: exclusive scan of nb real bucket counts (nb <= 1024); rp[n]=e
__global__ __launch_bounds__(1024) void k_bscan(const int* __restrict__ realcnt,
                                                int* __restrict__ boff,
                                                int* __restrict__ rp,
                                                int nb, int n, int e) {
    __shared__ int sh[1024];
    int t = threadIdx.x;
    sh[t] = (t < nb) ? realcnt[t] : 0;
    __syncthreads();
    for (int off = 1; off < 1024; off <<= 1) {
        int u = (t >= off) ? sh[t - off] : 0;
        __syncthreads();
        sh[t] += u;
        __syncthreads();
    }
    if (t < nb) boff[t] = (t == 0) ? 0 : sh[t - 1];
    if (t == 0) rp[n] = e;
}

// one block per bucket: histogram (skip sentinels) -> scan -> rp -> csr
__global__ __launch_bounds__(256) void k_build(const unsigned* __restrict__ ebuf,
                                               const int* __restrict__ gcnt,
                                               const int* __restrict__ boff,
                                               int* __restrict__ rp,
                                               int* __restrict__ csr, int n) {
    __shared__ int bins[128];
    __shared__ int incl[128];
    __shared__ int cur[128];
    int b = blockIdx.x, t = threadIdx.x;
    if (t < 128) bins[t] = 0;
    __syncthreads();
    int c = gcnt[b * 16]; if (c > CAP) c = CAP;
    const unsigned* seg = ebuf + ((size_t)b * CAP);
    for (int j = t; j < c; j += 256) {
        unsigned w = seg[j];
        if (w != 0xFFFFFFFFu) atomicAdd(&bins[(w >> 17) & 127], 1);
    }
    __syncthreads();
    if (t < 128) incl[t] = bins[t];
    __syncthreads();
    for (int off = 1; off < 128; off <<= 1) {
        int u = (t < 128 && t >= off) ? incl[t - off] : 0;
        __syncthreads();
        if (t < 128) incl[t] += u;
        __syncthreads();
    }
    int base = boff[b];
    if (t < 128) {
        int ex = (t == 0) ? 0 : incl[t - 1];
        cur[t] = ex;
        int node = b * 128 + t;
        if (node < n) rp[node] = base + ex;
    }
    __syncthreads();
    for (int j = t; j < c; j += 256) {
        unsigned w = seg[j];
        if (w != 0xFFFFFFFFu) {
            int slot = atomicAdd(&cur[(w >> 17) & 127], 1);
            csr[base + slot] = (int)(w & 0x1FFFF);
        }
    }
}

// ---------------- active set (roots + their in-neighbors) ----------------
__global__ void k_flag(const int* __restrict__ roots, int nr,
                       const int* __restrict__ rp, const int* __restrict__ csr,
                       int* __restrict__ af) {
    int i = blockIdx.x * blockDim.x + threadIdx.x;
    if (i >= nr) return;
    int r = roots[i];
    af[r] = 1;
    int e = rp[r + 1];
    for (int k = rp[r]; k < e; ++k) af[csr[k]] = 1;
}

__global__ void k_compact(const int* __restrict__ af, int* __restrict__ list,
                          int* __restrict__ cnt, int n) {
    int i = blockIdx.x * blockDim.x + threadIdx.x;
    if (i < n && af[i]) {
        int p = atomicAdd(cnt, 1);
        list[p] = i;
    }
}

// ---------------- segment sum fused with GIN update ----------------
// z[j] = (1+eps)*x[node] + sum_{s in N(node)} x[s]   (bf16 out, f32 accum)
// 16 lanes per output row; max-TLP standalone kernel (R9 lesson).
__global__ __launch_bounds__(256) void k_segz(const unsigned short* __restrict__ xb,
                                              const int* __restrict__ rp,
                                              const int* __restrict__ csr,
                                              const float* __restrict__ epsp,
                                              unsigned short* __restrict__ zout,
                                              const int* __restrict__ list,
                                              const int* __restrict__ cntp, int n) {
    int gid = blockIdx.x * 256 + threadIdx.x;
    int j = gid >> 4, lane = gid & 15;
    int rows = n;
    if (cntp) { int c = *cntp; rows = c < n ? c : n; }
    if (j >= rows) return;
    int node = list ? list[j] : j;
    int b = rp[node], e = rp[node + 1];
    float s0[8], s1[8];
#pragma unroll
    for (int q = 0; q < 8; ++q) { s0[q] = 0.f; s1[q] = 0.f; }
    int k = b;
    for (; k + 1 < e; k += 2) {
        bf16x8 v0 = *(const bf16x8*)&xb[(size_t)csr[k]     * 128 + lane * 8];
        bf16x8 v1 = *(const bf16x8*)&xb[(size_t)csr[k + 1] * 128 + lane * 8];
#pragma unroll
        for (int q = 0; q < 8; ++q) { s0[q] += (float)v0[q]; s1[q] += (float)v1[q]; }
    }
    if (k < e) {
        bf16x8 v0 = *(const bf16x8*)&xb[(size_t)csr[k] * 128 + lane * 8];
#pragma unroll
        for (int q = 0; q < 8; ++q) s0[q] += (float)v0[q];
    }
    const float epsv = 1.0f + epsp[0];
    bf16x8 xv = *(const bf16x8*)&xb[(size_t)node * 128 + lane * 8];
    bf16x8 o;
#pragma unroll
    for (int q = 0; q < 8; ++q)
        o[q] = (__bf16)(epsv * (float)xv[q] + s0[q] + s1[q]);
    *(bf16x8*)&zout[(size_t)j * 128 + lane * 8] = o;
}

// ---------------- MLP: out = relu( relu(z@w1+b1) @ w2 + b2 ) ----------------
// BM=128 rows/block, 256 threads = 4 waves in 2x2 over the 128x128 output.
// LDS = z/h/out tile only (34.8 KB); B read from global (L2-hot).
// Output routed through LDS -> bf16x8 global stores (full-line writes even
// when rows are list-scattered).
__global__ __launch_bounds__(256) void k_mlp(const unsigned short* __restrict__ zbuf,
                                             const unsigned short* __restrict__ w1T,
                                             const float* __restrict__ b1,
                                             const unsigned short* __restrict__ w2T,
                                             const float* __restrict__ b2,
                                             unsigned short* __restrict__ out,
                                             const int* __restrict__ list,
                                             const int* __restrict__ cntp, int nrows) {
    __shared__ unsigned short zt[128 * LDR];   // 34.8 KB
    const int t = threadIdx.x;
    int rows = nrows;
    if (cntp) { int c = *cntp; rows = c < nrows ? c : nrows; }
    const int row0 = blockIdx.x * 128;
    if (row0 >= rows) return;

    // stage z tile (coalesced from zbuf)
    for (int i = t; i < 2048; i += 256) {
        int r = i >> 4, c = i & 15;
        int g = row0 + r;
        bf16x8 zv;
        if (g < rows) {
            zv = *(const bf16x8*)&zbuf[(size_t)g * 128 + c * 8];
        } else {
#pragma unroll
            for (int q = 0; q < 8; ++q) zv[q] = (__bf16)0.0f;
        }
        *(bf16x8*)&zt[r * LDR + c * 8] = zv;
    }
    __syncthreads();

    const int lane = t & 63;
    const int wm = (t >> 7) & 1, wn = (t >> 6) & 1;
    const int lr = lane & 15, lk = lane >> 4;

    f32x4 zero4 = {0.f, 0.f, 0.f, 0.f};
    f32x4 acc[4][4];
#pragma unroll
    for (int mt = 0; mt < 4; ++mt)
#pragma unroll
        for (int nt = 0; nt < 4; ++nt) acc[mt][nt] = zero4;

    // -------- GEMM1: z @ w1 (B from global, L2-resident) --------
#pragma unroll
    for (int kb = 0; kb < 4; ++kb) {
        const int c = kb * 4 + lk;
        bf16x8 a[4];
#pragma unroll
        for (int mt = 0; mt < 4; ++mt)
            a[mt] = *(const bf16x8*)&zt[(wm * 64 + mt * 16 + lr) * LDR + c * 8];
#pragma unroll
        for (int nt = 0; nt < 4; ++nt) {
            bf16x8 b = *(const bf16x8*)&w1T[(wn * 64 + nt * 16 + lr) * 128 + c * 8];
#pragma unroll
            for (int mt = 0; mt < 4; ++mt)
                acc[mt][nt] = __builtin_amdgcn_mfma_f32_16x16x32_bf16(a[mt], b, acc[mt][nt], 0, 0, 0);
        }
    }
    __syncthreads();   // all zt reads done before in-place h overwrite

    // h = relu(acc + b1) -> zt (in place)
#pragma unroll
    for (int nt = 0; nt < 4; ++nt) {
        int col = wn * 64 + nt * 16 + lr;
        float bv = b1[col];
#pragma unroll
        for (int mt = 0; mt < 4; ++mt)
#pragma unroll
            for (int q = 0; q < 4; ++q) {
                int hr = wm * 64 + mt * 16 + lk * 4 + q;
                float hv = fmaxf(acc[mt][nt][q] + bv, 0.f);
                *(__bf16*)&zt[hr * LDR + col] = (__bf16)hv;
            }
    }
    __syncthreads();

    // -------- GEMM2: h @ w2 --------
    f32x4 acc2[4][4];
#pragma unroll
    for (int mt = 0; mt < 4; ++mt)
#pragma unroll
        for (int nt = 0; nt < 4; ++nt) acc2[mt][nt] = zero4;
#pragma unroll
    for (int kb = 0; kb < 4; ++kb) {
        const int c = kb * 4 + lk;
        bf16x8 a[4];
#pragma unroll
        for (int mt = 0; mt < 4; ++mt)
            a[mt] = *(const bf16x8*)&zt[(wm * 64 + mt * 16 + lr) * LDR + c * 8];
#pragma unroll
        for (int nt = 0; nt < 4; ++nt) {
            bf16x8 b = *(const bf16x8*)&w2T[(wn * 64 + nt * 16 + lr) * 128 + c * 8];
#pragma unroll
            for (int mt = 0; mt < 4; ++mt)
                acc2[mt][nt] = __builtin_amdgcn_mfma_f32_16x16x32_bf16(a[mt], b, acc2[mt][nt], 0, 0, 0);
        }
    }
    __syncthreads();   // all zt (h) reads done before out-tile overwrite

    // out-tile = relu(acc2 + b2) -> zt (in place)
#pragma unroll
    for (int nt = 0; nt < 4; ++nt) {
        int col = wn * 64 + nt * 16 + lr;
        float bv = b2[col];
#pragma unroll
        for (int mt = 0; mt < 4; ++mt)
#pragma unroll
            for (int q = 0; q < 4; ++q) {
                int orow = wm * 64 + mt * 16 + lk * 4 + q;
                float ov = fmaxf(acc2[mt][nt][q] + bv, 0.f);
                *(__bf16*)&zt[orow * LDR + col] = (__bf16)ov;
            }
    }
    __syncthreads();

    // vectorized global stores: one bf16x8 per 16B chunk, full-line rows
    for (int i = t; i < 2048; i += 256) {
        int r = i >> 4, c = i & 15;
        int g = row0 + r;
        if (g < rows) {
            int node = list ? list[g] : g;
            *(bf16x8*)&out[(size_t)node * 128 + c * 8] =
                *(const bf16x8*)&zt[r * LDR + c * 8];
        }
    }
}

// ---------------- layer 2 at roots only ----------------
__global__ __launch_bounds__(128) void k_root(const unsigned short* __restrict__ x2,
                                              const int* __restrict__ rp,
                                              const int* __restrict__ csr,
                                              const int* __restrict__ roots,
                                              const float* __restrict__ epsp,
                                              const float* __restrict__ wa,
                                              const float* __restrict__ ba,
                                              const float* __restrict__ wb,
                                              const float* __restrict__ bb,
                                              float* __restrict__ out) {
    __shared__ float hin[128];
    __shared__ float h[64];
    int r = blockIdx.x, t = threadIdx.x;
    int node = roots[r];
    float s = (1.0f + epsp[0]) * (float)(*(const __bf16*)&x2[(size_t)node * 128 + t]);
    int b = rp[node], e = rp[node + 1];
    for (int k = b; k < e; ++k)
        s += (float)(*(const __bf16*)&x2[(size_t)csr[k] * 128 + t]);
    hin[t] = s;
    __syncthreads();
    if (t < 64) {
        float a = ba[t];
        for (int k = 0; k < 128; ++k) a += hin[k] * wa[k * 64 + t];
        h[t] = fmaxf(a, 0.f);
    }
    __syncthreads();
    if (t < 64) {
        float a = bb[t];
        for (int k = 0; k < 64; ++k) a += h[k] * wb[k * 64 + t];
        out[(size_t)r * 64 + t] = a;
    }
}

extern "C" void kernel_launch(void* const* d_in, const int* in_sizes, int n_in,
                              void* d_out, int out_size, void* d_ws, size_t ws_size,
                              hipStream_t stream) {
    const float* x    = (const float*)d_in[0];
    const int*   ei   = (const int*)d_in[1];
    const int*   root = (const int*)d_in[2];
    const float* eps0 = (const float*)d_in[3];
    const float* w0a  = (const float*)d_in[4];
    const float* b0a  = (const float*)d_in[5];
    const float* w0b  = (const float*)d_in[6];
    const float* b0b  = (const float*)d_in[7];
    const float* eps1 = (const float*)d_in[8];
    const float* w1a  = (const float*)d_in[9];
    const float* b1a  = (const float*)d_in[10];
    const float* w1b  = (const float*)d_in[11];
    const float* b1b  = (const float*)d_in[12];
    const float* eps2 = (const float*)d_in[13];
    const float* w2a  = (const float*)d_in[14];
    const float* b2a  = (const float*)d_in[15];
    const float* w2b  = (const float*)d_in[16];
    const float* b2b  = (const float*)d_in[17];

    const int N  = in_sizes[0] / 128;
    const int E  = in_sizes[1] / 2;
    const int NR = in_sizes[2];
    const int MAXACT = 65536;
    const int NB = (N + 127) / 128;           // buckets of 128 nodes (782)
    const int* src = ei;
    const int* dst = ei + E;

    // ---- workspace layout ----
    char* p = (char*)d_ws;
    unsigned short* xb = (unsigned short*)p; p += (size_t)N * 128 * 2;        // 25.6 MB
    unsigned short* x1 = (unsigned short*)p; p += (size_t)N * 128 * 2;        // 25.6 MB
    unsigned short* z0 = (unsigned short*)p; p += (size_t)N * 128 * 2;        // 25.6 MB
    // shared region: ebuf (CSR build) then x2 (mlp1 output) — disjoint in time
    char* shared0 = p;
    size_t ebuf_bytes = (size_t)NB * CAP * 4;                                 // 25.6 MB
    size_t x2_bytes   = (size_t)N * 128 * 2;                                  // 25.6 MB
    p += (ebuf_bytes > x2_bytes ? ebuf_bytes : x2_bytes);
    unsigned*       ebuf = (unsigned*)shared0;
    unsigned short* x2   = (unsigned short*)shared0;
    unsigned short* z1   = (unsigned short*)p; p += (size_t)MAXACT * 128 * 2; // 16.8 MB
    unsigned short* wT   = (unsigned short*)p; p += 4 * 128 * 128 * 2;
    int* rp      = (int*)p; p += (size_t)(N + 64) * 4;
    int* list    = (int*)p; p += (size_t)(N + 64) * 4;
    int* boff    = (int*)p; p += 4096;
    // zeroed region (single memset): af | cnt | gcnt | realcnt
    char* zbeg = p;
    int* af      = (int*)p; p += (size_t)(N + 64) * 4;
    int* cnt     = (int*)p; p += 256;
    int* gcnt    = (int*)p; p += (size_t)NB * 16 * 4;      // 64B-padded counters
    int* realcnt = (int*)p; p += (size_t)(NB + 64) * 4;
    size_t zbytes = (size_t)(p - zbeg);
    int* csr     = (int*)p; p += (size_t)E * 4;
    unsigned short* w0aT = wT;
    unsigned short* w0bT = wT + 16384;
    unsigned short* w1aT = wT + 32768;
    unsigned short* w1bT = wT + 49152;

    // ---- conversions ----
    k_cvt_x<<<(N * 128 / 8 + 255) / 256, 256, 0, stream>>>((const float4*)x, xb, (long)N * 16);
    k_cvt_w4<<<256, 256, 0, stream>>>(w0a, w0b, w1a, w1b, wT);

    // ---- CSR build ----
    hipMemsetAsync(zbeg, 0, zbytes, stream);
    k_scatter<<<256, 512, 0, stream>>>(src, dst, gcnt, realcnt, ebuf, E, NB);
    k_bscan<<<1, 1024, 0, stream>>>(realcnt, boff, rp, NB, N, E);
    k_build<<<NB, 256, 0, stream>>>(ebuf, gcnt, boff, rp, csr, N);

    // ---- active set ----
    k_flag<<<(NR + 255) / 256, 256, 0, stream>>>(root, NR, rp, csr, af);
    k_compact<<<(N + 255) / 256, 256, 0, stream>>>(af, list, cnt, N);

    // ---- layer 0 (all nodes) ----
    k_segz<<<(N * 16 + 255) / 256, 256, 0, stream>>>(xb, rp, csr, eps0, z0,
                                                     nullptr, nullptr, N);
    k_mlp<<<(N + 127) / 128, 256, 0, stream>>>(z0, w0aT, b0a, w0bT, b0b,
                                               x1, nullptr, nullptr, N);
    // ---- layer 1 (active set only) ----
    k_segz<<<(MAXACT * 16 + 255) / 256, 256, 0, stream>>>(x1, rp, csr, eps1, z1,
                                                          list, cnt, MAXACT);
    k_mlp<<<(MAXACT + 127) / 128, 256, 0, stream>>>(z1, w1aT, b1a, w1bT, b1b,
                                                    x2, list, cnt, MAXACT);
    // ---- layer 2 (roots only) ----
    k_root<<<NR, 128, 0, stream>>>(x2, rp, csr, root, eps2, w2a, b2a, w2b, b2b,
                                   (float*)d_out);
}

// Round 13
// 229.099 us; speedup vs baseline: 1.4055x; 1.0168x over previous
//
#include <hip/hip_runtime.h>

// ---------------------------------------------------------------------------
// GIN 3-layer forward on MI355X (gfx950).
//   - features/weights bf16 node-major (f32 accumulate). R11 lesson: slice-
//     major 32B granules halve line efficiency and XCD pinning via blockIdx
//     is unreliable -> node-major 256B rows (gather at ~6.6 TB/s logical,
//     the practical random-gather ceiling; R12 profile).
//   - CSR build: LDS-binned scatter with FULL-LINE flushes (sentinel-padded
//     64B bursts; this chip's L2 does NOT merge scattered partial-line
//     stores). 1024 threads/block (16 waves/CU): binning is LDS-atomic
//     LATENCY bound -> TLP is the lever (R12: 512t was -20us vs 256t).
//   - k_segz: segment-sum gather (16 lanes/node, bf16x8, f32 accum) fused
//     with GIN update z=(1+eps)x+sum. Standalone max-TLP kernel (R9 lesson).
//   - k_mlp: MFMA 16x16x32 bf16, BM=128, 4 waves, LDS = z/h tile only
//     (34.8 KB); B from global (L2-resident). Output routed through LDS ->
//     bf16x8 stores = full-line writes even for list-scattered rows.
//   - layer 1 only on active set = roots U in-neighbors(roots)
//   - layer 2 only at the 1024 roots
//   NOTE: edge packing assumes N <= 2^17; bins assume N <= 100352.
// ---------------------------------------------------------------------------

typedef __bf16  bf16x8 __attribute__((ext_vector_type(8)));
typedef float   f32x4  __attribute__((ext_vector_type(4)));

#define NBINS 784     // >= (N+127)/128
#define BCAP  38      // words per LDS bin (per-bin lambda ~8)
#define CAP   8192    // words per global bucket cell (real ~2048 + pads)
#define LDR   136     // MLP LDS row stride in shorts (+8 pad)

// ---------------- conversion kernels ----------------
__global__ __launch_bounds__(256) void k_cvt_x(const float4* __restrict__ in,
                                               unsigned short* __restrict__ outb,
                                               long n8) {
    long i = (long)blockIdx.x * 256 + threadIdx.x;
    if (i >= n8) return;
    float4 a = in[2 * i], b = in[2 * i + 1];
    bf16x8 v;
    v[0] = (__bf16)a.x; v[1] = (__bf16)a.y; v[2] = (__bf16)a.z; v[3] = (__bf16)a.w;
    v[4] = (__bf16)b.x; v[5] = (__bf16)b.y; v[6] = (__bf16)b.z; v[7] = (__bf16)b.w;
    *(bf16x8*)&outb[i * 8] = v;
}

// 4 weight matrices -> transposed bf16, contiguous output (4 x 128 x 128)
__global__ __launch_bounds__(256) void k_cvt_w4(const float* __restrict__ wa,
                                                const float* __restrict__ wb,
                                                const float* __restrict__ wc,
                                                const float* __restrict__ wd,
                                                unsigned short* __restrict__ out) {
    int i = blockIdx.x * 256 + threadIdx.x;    // 65536
    int m = i >> 14, j = i & 16383;
    const float* w = (m == 0) ? wa : (m == 1) ? wb : (m == 2) ? wc : wd;
    int k = j >> 7, n = j & 127;
    *(__bf16*)&out[m * 16384 + n * 128 + k] = (__bf16)w[j];
}

// ---------------- LDS-binned scatter with full-line flush ----------------
// 1024 threads (16 waves/CU): binning is LDS-atomic latency bound; max TLP.
__global__ __launch_bounds__(1024) void k_scatter(const int* __restrict__ src,
                                                  const int* __restrict__ dst,
                                                  int* __restrict__ gcnt,     // NB*16 padded
                                                  int* __restrict__ realcnt,  // NB
                                                  unsigned* __restrict__ ebuf,
                                                  int e, int nb) {
    __shared__ unsigned lbuf[NBINS * BCAP];   // 119.2 KB
    __shared__ int lcnt[NBINS];
    __shared__ int sbase[NBINS];
    const int t = threadIdx.x;
    for (int b = t; b < nb; b += 1024) lcnt[b] = 0;
    __syncthreads();

    const int per = (((e + 255) / 256) + 7) & ~7;   // 8-aligned slice, 256 blocks
    const int beg = blockIdx.x * per;
    const int end = (beg + per < e) ? beg + per : e;

    for (int base = beg; base < end; base += 8192) {
        int i0 = base + t * 8;
        if (i0 >= end) continue;
        if (i0 + 8 <= end) {
            int4 s0 = *(const int4*)&src[i0];
            int4 s1 = *(const int4*)&src[i0 + 4];
            int4 d0 = *(const int4*)&dst[i0];
            int4 d1 = *(const int4*)&dst[i0 + 4];
            int ss[8] = {s0.x, s0.y, s0.z, s0.w, s1.x, s1.y, s1.z, s1.w};
            int dd[8] = {d0.x, d0.y, d0.z, d0.w, d1.x, d1.y, d1.z, d1.w};
#pragma unroll
            for (int q = 0; q < 8; ++q) {
                int b = dd[q] >> 7;
                int p = atomicAdd(&lcnt[b], 1);
                if (p < BCAP)
                    lbuf[b * BCAP + p] =
                        (unsigned)ss[q] | ((unsigned)(dd[q] & 127) << 17);
            }
        } else {
            int lim = (i0 + 8 < end) ? i0 + 8 : end;
            for (int i = i0; i < lim; ++i) {
                int d = dst[i];
                int b = d >> 7;
                int p = atomicAdd(&lcnt[b], 1);
                if (p < BCAP)
                    lbuf[b * BCAP + p] =
                        (unsigned)src[i] | ((unsigned)(d & 127) << 17);
            }
        }
    }
    __syncthreads();

    // phase 1: reserve cell ranges
    for (int b = t; b < nb; b += 1024) {
        int r = lcnt[b]; if (r > BCAP) r = BCAP;
        int bb = 0;
        if (r > 0) {
            int nf = (r + 15) & ~15;
            bb = atomicAdd(&gcnt[b * 16], nf);
            atomicAdd(&realcnt[b], r);
        }
        sbase[b] = bb;
    }
    __syncthreads();

    // phase 2: cooperative full-line copies (16-lane group per bin, 64 groups)
    const int wave = t >> 6, lane = t & 63;
    const int gidx = wave * 4 + (lane >> 4), sub = lane & 15;
    for (int b = gidx; b < nb; b += 64) {
        int r = lcnt[b]; if (r > BCAP) r = BCAP;
        if (r == 0) continue;
        int nf = (r + 15) & ~15;
        int base2 = sbase[b];
        unsigned* cell = ebuf + (size_t)b * CAP;
        for (int j = sub; j < nf; j += 16) {
            unsigned v = (j < r) ? lbuf[b * BCAP + j] : 0xFFFFFFFFu;
            if (base2 + j < CAP) cell[base2 + j] = v;
        }
    }
}

// one block: exclusive scan of nb real bucket counts (nb <= 1024); rp[n]=e
__global__ __launch_bounds__(1024) void k_bscan(const int* __restrict__ realcnt,
                                                int* __restrict__ boff,
                                                int* __restrict__ rp,
                                                int nb, int n, int e) {
    __shared__ int sh[1024];
    int t = threadIdx.x;
    sh[t] = (t < nb) ? realcnt[t] : 0;
    __syncthreads();
    for (int off = 1; off < 1024; off <<= 1) {
        int u = (t >= off) ? sh[t - off] : 0;
        __syncthreads();
        sh[t] += u;
        __syncthreads();
    }
    if (t < nb) boff[t] = (t == 0) ? 0 : sh[t - 1];
    if (t == 0) rp[n] = e;
}

// one block per bucket: histogram (skip sentinels) -> scan -> rp -> csr
// 512 threads: both LDS-atomic loops are latency bound; halve serial depth.
__global__ __launch_bounds__(512) void k_build(const unsigned* __restrict__ ebuf,
                                               const int* __restrict__ gcnt,
                                               const int* __restrict__ boff,
                                               int* __restrict__ rp,
                                               int* __restrict__ csr, int n) {
    __shared__ int bins[128];
    __shared__ int incl[128];
    __shared__ int cur[128];
    int b = blockIdx.x, t = threadIdx.x;
    if (t < 128) bins[t] = 0;
    __syncthreads();
    int c = gcnt[b * 16]; if (c > CAP) c = CAP;
    const unsigned* seg = ebuf + ((size_t)b * CAP);
    for (int j = t; j < c; j += 512) {
        unsigned w = seg[j];
        if (w != 0xFFFFFFFFu) atomicAdd(&bins[(w >> 17) & 127], 1);
    }
    __syncthreads();
    if (t < 128) incl[t] = bins[t];
    __syncthreads();
    for (int off = 1; off < 128; off <<= 1) {
        int u = (t < 128 && t >= off) ? incl[t - off] : 0;
        __syncthreads();
        if (t < 128) incl[t] += u;
        __syncthreads();
    }
    int base = boff[b];
    if (t < 128) {
        int ex = (t == 0) ? 0 : incl[t - 1];
        cur[t] = ex;
        int node = b * 128 + t;
        if (node < n) rp[node] = base + ex;
    }
    __syncthreads();
    for (int j = t; j < c; j += 512) {
        unsigned w = seg[j];
        if (w != 0xFFFFFFFFu) {
            int slot = atomicAdd(&cur[(w >> 17) & 127], 1);
            csr[base + slot] = (int)(w & 0x1FFFF);
        }
    }
}

// ---------------- active set (roots + their in-neighbors) ----------------
__global__ void k_flag(const int* __restrict__ roots, int nr,
                       const int* __restrict__ rp, const int* __restrict__ csr,
                       int* __restrict__ af) {
    int i = blockIdx.x * blockDim.x + threadIdx.x;
    if (i >= nr) return;
    int r = roots[i];
    af[r] = 1;
    int e = rp[r + 1];
    for (int k = rp[r]; k < e; ++k) af[csr[k]] = 1;
}

__global__ void k_compact(const int* __restrict__ af, int* __restrict__ list,
                          int* __restrict__ cnt, int n) {
    int i = blockIdx.x * blockDim.x + threadIdx.x;
    if (i < n && af[i]) {
        int p = atomicAdd(cnt, 1);
        list[p] = i;
    }
}

// ---------------- segment sum fused with GIN update ----------------
// z[j] = (1+eps)*x[node] + sum_{s in N(node)} x[s]   (bf16 out, f32 accum)
// 16 lanes per output row; max-TLP standalone kernel (R9 lesson).
__global__ __launch_bounds__(256) void k_segz(const unsigned short* __restrict__ xb,
                                              const int* __restrict__ rp,
                                              const int* __restrict__ csr,
                                              const float* __restrict__ epsp,
                                              unsigned short* __restrict__ zout,
                                              const int* __restrict__ list,
                                              const int* __restrict__ cntp, int n) {
    int gid = blockIdx.x * 256 + threadIdx.x;
    int j = gid >> 4, lane = gid & 15;
    int rows = n;
    if (cntp) { int c = *cntp; rows = c < n ? c : n; }
    if (j >= rows) return;
    int node = list ? list[j] : j;
    int b = rp[node], e = rp[node + 1];
    float s0[8], s1[8];
#pragma unroll
    for (int q = 0; q < 8; ++q) { s0[q] = 0.f; s1[q] = 0.f; }
    int k = b;
    for (; k + 1 < e; k += 2) {
        bf16x8 v0 = *(const bf16x8*)&xb[(size_t)csr[k]     * 128 + lane * 8];
        bf16x8 v1 = *(const bf16x8*)&xb[(size_t)csr[k + 1] * 128 + lane * 8];
#pragma unroll
        for (int q = 0; q < 8; ++q) { s0[q] += (float)v0[q]; s1[q] += (float)v1[q]; }
    }
    if (k < e) {
        bf16x8 v0 = *(const bf16x8*)&xb[(size_t)csr[k] * 128 + lane * 8];
#pragma unroll
        for (int q = 0; q < 8; ++q) s0[q] += (float)v0[q];
    }
    const float epsv = 1.0f + epsp[0];
    bf16x8 xv = *(const bf16x8*)&xb[(size_t)node * 128 + lane * 8];
    bf16x8 o;
#pragma unroll
    for (int q = 0; q < 8; ++q)
        o[q] = (__bf16)(epsv * (float)xv[q] + s0[q] + s1[q]);
    *(bf16x8*)&zout[(size_t)j * 128 + lane * 8] = o;
}

// ---------------- MLP: out = relu( relu(z@w1+b1) @ w2 + b2 ) ----------------
// BM=128 rows/block, 256 threads = 4 waves in 2x2 over the 128x128 output.
// LDS = z/h/out tile only (34.8 KB); B read from global (L2-hot).
// Output routed through LDS -> bf16x8 global stores (full-line writes even
// when rows are list-scattered).
__global__ __launch_bounds__(256) void k_mlp(const unsigned short* __restrict__ zbuf,
                                             const unsigned short* __restrict__ w1T,
                                             const float* __restrict__ b1,
                                             const unsigned short* __restrict__ w2T,
                                             const float* __restrict__ b2,
                                             unsigned short* __restrict__ out,
                                             const int* __restrict__ list,
                                             const int* __restrict__ cntp, int nrows) {
    __shared__ unsigned short zt[128 * LDR];   // 34.8 KB
    const int t = threadIdx.x;
    int rows = nrows;
    if (cntp) { int c = *cntp; rows = c < nrows ? c : nrows; }
    const int row0 = blockIdx.x * 128;
    if (row0 >= rows) return;

    // stage z tile (coalesced from zbuf)
    for (int i = t; i < 2048; i += 256) {
        int r = i >> 4, c = i & 15;
        int g = row0 + r;
        bf16x8 zv;
        if (g < rows) {
            zv = *(const bf16x8*)&zbuf[(size_t)g * 128 + c * 8];
        } else {
#pragma unroll
            for (int q = 0; q < 8; ++q) zv[q] = (__bf16)0.0f;
        }
        *(bf16x8*)&zt[r * LDR + c * 8] = zv;
    }
    __syncthreads();

    const int lane = t & 63;
    const int wm = (t >> 7) & 1, wn = (t >> 6) & 1;
    const int lr = lane & 15, lk = lane >> 4;

    f32x4 zero4 = {0.f, 0.f, 0.f, 0.f};
    f32x4 acc[4][4];
#pragma unroll
    for (int mt = 0; mt < 4; ++mt)
#pragma unroll
        for (int nt = 0; nt < 4; ++nt) acc[mt][nt] = zero4;

    // -------- GEMM1: z @ w1 (B from global, L2-resident) --------
#pragma unroll
    for (int kb = 0; kb < 4; ++kb) {
        const int c = kb * 4 + lk;
        bf16x8 a[4];
#pragma unroll
        for (int mt = 0; mt < 4; ++mt)
            a[mt] = *(const bf16x8*)&zt[(wm * 64 + mt * 16 + lr) * LDR + c * 8];
#pragma unroll
        for (int nt = 0; nt < 4; ++nt) {
            bf16x8 b = *(const bf16x8*)&w1T[(wn * 64 + nt * 16 + lr) * 128 + c * 8];
#pragma unroll
            for (int mt = 0; mt < 4; ++mt)
                acc[mt][nt] = __builtin_amdgcn_mfma_f32_16x16x32_bf16(a[mt], b, acc[mt][nt], 0, 0, 0);
        }
    }
    __syncthreads();   // all zt reads done before in-place h overwrite

    // h = relu(acc + b1) -> zt (in place)
#pragma unroll
    for (int nt = 0; nt < 4; ++nt) {
        int col = wn * 64 + nt * 16 + lr;
        float bv = b1[col];
#pragma unroll
        for (int mt = 0; mt < 4; ++mt)
#pragma unroll
            for (int q = 0; q < 4; ++q) {
                int hr = wm * 64 + mt * 16 + lk * 4 + q;
                float hv = fmaxf(acc[mt][nt][q] + bv, 0.f);
                *(__bf16*)&zt[hr * LDR + col] = (__bf16)hv;
            }
    }
    __syncthreads();

    // -------- GEMM2: h @ w2 --------
    f32x4 acc2[4][4];
#pragma unroll
    for (int mt = 0; mt < 4; ++mt)
#pragma unroll
        for (int nt = 0; nt < 4; ++nt) acc2[mt][nt] = zero4;
#pragma unroll
    for (int kb = 0; kb < 4; ++kb) {
        const int c = kb * 4 + lk;
        bf16x8 a[4];
#pragma unroll
        for (int mt = 0; mt < 4; ++mt)
            a[mt] = *(const bf16x8*)&zt[(wm * 64 + mt * 16 + lr) * LDR + c * 8];
#pragma unroll
        for (int nt = 0; nt < 4; ++nt) {
            bf16x8 b = *(const bf16x8*)&w2T[(wn * 64 + nt * 16 + lr) * 128 + c * 8];
#pragma unroll
            for (int mt = 0; mt < 4; ++mt)
                acc2[mt][nt] = __builtin_amdgcn_mfma_f32_16x16x32_bf16(a[mt], b, acc2[mt][nt], 0, 0, 0);
        }
    }
    __syncthreads();   // all zt (h) reads done before out-tile overwrite

    // out-tile = relu(acc2 + b2) -> zt (in place)
#pragma unroll
    for (int nt = 0; nt < 4; ++nt) {
        int col = wn * 64 + nt * 16 + lr;
        float bv = b2[col];
#pragma unroll
        for (int mt = 0; mt < 4; ++mt)
#pragma unroll
            for (int q = 0; q < 4; ++q) {
                int orow = wm * 64 + mt * 16 + lk * 4 + q;
                float ov = fmaxf(acc2[mt][nt][q] + bv, 0.f);
                *(__bf16*)&zt[orow * LDR + col] = (__bf16)ov;
            }
    }
    __syncthreads();

    // vectorized global stores: one bf16x8 per 16B chunk, full-line rows
    for (int i = t; i < 2048; i += 256) {
        int r = i >> 4, c = i & 15;
        int g = row0 + r;
        if (g < rows) {
            int node = list ? list[g] : g;
            *(bf16x8*)&out[(size_t)node * 128 + c * 8] =
                *(const bf16x8*)&zt[r * LDR + c * 8];
        }
    }
}

// ---------------- layer 2 at roots only ----------------
__global__ __launch_bounds__(128) void k_root(const unsigned short* __restrict__ x2,
                                              const int* __restrict__ rp,
                                              const int* __restrict__ csr,
                                              const int* __restrict__ roots,
                                              const float* __restrict__ epsp,
                                              const float* __restrict__ wa,
                                              const float* __restrict__ ba,
                                              const float* __restrict__ wb,
                                              const float* __restrict__ bb,
                                              float* __restrict__ out) {
    __shared__ float hin[128];
    __shared__ float h[64];
    int r = blockIdx.x, t = threadIdx.x;
    int node = roots[r];
    float s = (1.0f + epsp[0]) * (float)(*(const __bf16*)&x2[(size_t)node * 128 + t]);
    int b = rp[node], e = rp[node + 1];
    for (int k = b; k < e; ++k)
        s += (float)(*(const __bf16*)&x2[(size_t)csr[k] * 128 + t]);
    hin[t] = s;
    __syncthreads();
    if (t < 64) {
        float a = ba[t];
        for (int k = 0; k < 128; ++k) a += hin[k] * wa[k * 64 + t];
        h[t] = fmaxf(a, 0.f);
    }
    __syncthreads();
    if (t < 64) {
        float a = bb[t];
        for (int k = 0; k < 64; ++k) a += h[k] * wb[k * 64 + t];
        out[(size_t)r * 64 + t] = a;
    }
}

extern "C" void kernel_launch(void* const* d_in, const int* in_sizes, int n_in,
                              void* d_out, int out_size, void* d_ws, size_t ws_size,
                              hipStream_t stream) {
    const float* x    = (const float*)d_in[0];
    const int*   ei   = (const int*)d_in[1];
    const int*   root = (const int*)d_in[2];
    const float* eps0 = (const float*)d_in[3];
    const float* w0a  = (const float*)d_in[4];
    const float* b0a  = (const float*)d_in[5];
    const float* w0b  = (const float*)d_in[6];
    const float* b0b  = (const float*)d_in[7];
    const float* eps1 = (const float*)d_in[8];
    const float* w1a  = (const float*)d_in[9];
    const float* b1a  = (const float*)d_in[10];
    const float* w1b  = (const float*)d_in[11];
    const float* b1b  = (const float*)d_in[12];
    const float* eps2 = (const float*)d_in[13];
    const float* w2a  = (const float*)d_in[14];
    const float* b2a  = (const float*)d_in[15];
    const float* w2b  = (const float*)d_in[16];
    const float* b2b  = (const float*)d_in[17];

    const int N  = in_sizes[0] / 128;
    const int E  = in_sizes[1] / 2;
    const int NR = in_sizes[2];
    const int MAXACT = 65536;
    const int NB = (N + 127) / 128;           // buckets of 128 nodes (782)
    const int* src = ei;
    const int* dst = ei + E;

    // ---- workspace layout ----
    char* p = (char*)d_ws;
    unsigned short* xb = (unsigned short*)p; p += (size_t)N * 128 * 2;        // 25.6 MB
    unsigned short* x1 = (unsigned short*)p; p += (size_t)N * 128 * 2;        // 25.6 MB
    unsigned short* z0 = (unsigned short*)p; p += (size_t)N * 128 * 2;        // 25.6 MB
    // shared region: ebuf (CSR build) then x2 (mlp1 output) — disjoint in time
    char* shared0 = p;
    size_t ebuf_bytes = (size_t)NB * CAP * 4;                                 // 25.6 MB
    size_t x2_bytes   = (size_t)N * 128 * 2;                                  // 25.6 MB
    p += (ebuf_bytes > x2_bytes ? ebuf_bytes : x2_bytes);
    unsigned*       ebuf = (unsigned*)shared0;
    unsigned short* x2   = (unsigned short*)shared0;
    unsigned short* z1   = (unsigned short*)p; p += (size_t)MAXACT * 128 * 2; // 16.8 MB
    unsigned short* wT   = (unsigned short*)p; p += 4 * 128 * 128 * 2;
    int* rp      = (int*)p; p += (size_t)(N + 64) * 4;
    int* list    = (int*)p; p += (size_t)(N + 64) * 4;
    int* boff    = (int*)p; p += 4096;
    // zeroed region (single memset): af | cnt | gcnt | realcnt
    char* zbeg = p;
    int* af      = (int*)p; p += (size_t)(N + 64) * 4;
    int* cnt     = (int*)p; p += 256;
    int* gcnt    = (int*)p; p += (size_t)NB * 16 * 4;      // 64B-padded counters
    int* realcnt = (int*)p; p += (size_t)(NB + 64) * 4;
    size_t zbytes = (size_t)(p - zbeg);
    int* csr     = (int*)p; p += (size_t)E * 4;
    unsigned short* w0aT = wT;
    unsigned short* w0bT = wT + 16384;
    unsigned short* w1aT = wT + 32768;
    unsigned short* w1bT = wT + 49152;

    // ---- conversions ----
    k_cvt_x<<<(N * 128 / 8 + 255) / 256, 256, 0, stream>>>((const float4*)x, xb, (long)N * 16);
    k_cvt_w4<<<256, 256, 0, stream>>>(w0a, w0b, w1a, w1b, wT);

    // ---- CSR build ----
    hipMemsetAsync(zbeg, 0, zbytes, stream);
    k_scatter<<<256, 1024, 0, stream>>>(src, dst, gcnt, realcnt, ebuf, E, NB);
    k_bscan<<<1, 1024, 0, stream>>>(realcnt, boff, rp, NB, N, E);
    k_build<<<NB, 512, 0, stream>>>(ebuf, gcnt, boff, rp, csr, N);

    // ---- active set ----
    k_flag<<<(NR + 255) / 256, 256, 0, stream>>>(root, NR, rp, csr, af);
    k_compact<<<(N + 255) / 256, 256, 0, stream>>>(af, list, cnt, N);

    // ---- layer 0 (all nodes) ----
    k_segz<<<(N * 16 + 255) / 256, 256, 0, stream>>>(xb, rp, csr, eps0, z0,
                                                     nullptr, nullptr, N);
    k_mlp<<<(N + 127) / 128, 256, 0, stream>>>(z0, w0aT, b0a, w0bT, b0b,
                                               x1, nullptr, nullptr, N);
    // ---- layer 1 (active set only) ----
    k_segz<<<(MAXACT * 16 + 255) / 256, 256, 0, stream>>>(x1, rp, csr, eps1, z1,
                                                          list, cnt, MAXACT);
    k_mlp<<<(MAXACT + 127) / 128, 256, 0, stream>>>(z1, w1aT, b1a, w1bT, b1b,
                                                    x2, list, cnt, MAXACT);
    // ---- layer 2 (roots only) ----
    k_root<<<NR, 128, 0, stream>>>(x2, rp, csr, root, eps2, w2a, b2a, w2b, b2b,
                                   (float*)d_out);
}

// Round 14
// 212.921 us; speedup vs baseline: 1.5123x; 1.0760x over previous
//
#include <hip/hip_runtime.h>

// ---------------------------------------------------------------------------
// GIN 3-layer forward on MI355X (gfx950).
//   - features/weights bf16 node-major (f32 accumulate). R11: slice-major /
//     XCD pinning regressed; node-major 256B rows gather at ~6.6 TB/s
//     logical = practical random-gather ceiling (R12/R13 profiles).
//   - k_scatter (merged): LDS-binned edge scatter with FULL-LINE flushes
//     (sentinel-padded 64B bursts; this chip's L2 does NOT merge scattered
//     partial-line stores) + x f32->bf16 conversion + weight transpose +
//     root bitmap, all hidden under the latency-bound binning (R14).
//   - k_build (merged): per-bucket histogram -> scan -> rp -> csr slotting,
//     flags root in-neighbors inline (af) via af_root bitmap.
//   - k_segz: segment-sum gather (16 lanes/node, bf16x8, f32 accum) fused
//     with GIN update z=(1+eps)x+sum. Standalone max-TLP kernel (R9 lesson).
//   - k_mlp: MFMA 16x16x32 bf16, BM=128, 4 waves, LDS z/h tile (34.8 KB);
//     B from global (L2-resident); output via LDS -> bf16x8 full-line stores.
//   - layer 1 only on active set = roots U in-neighbors(roots); layer 2 only
//     at the 1024 roots.
//   NOTE: edge packing assumes N <= 2^17; bins assume N <= 100352.
// ---------------------------------------------------------------------------

typedef __bf16  bf16x8 __attribute__((ext_vector_type(8)));
typedef float   f32x4  __attribute__((ext_vector_type(4)));

#define NBINS 784     // >= (N+127)/128
#define BCAP  38      // words per LDS bin (per-bin lambda ~8)
#define CAP   8192    // words per global bucket cell (real ~2048 + pads)
#define LDR   136     // MLP LDS row stride in shorts (+8 pad)

// ---------------- merged scatter + conversions + root flag ----------------
// 256 blocks x 1024 threads (16 waves/CU): binning is LDS-atomic latency
// bound; the streaming conversions hide under it (BW headroom ~5 TB/s).
__global__ __launch_bounds__(1024) void k_scatter(const int* __restrict__ src,
                                                  const int* __restrict__ dst,
                                                  int* __restrict__ gcnt,     // NB*16 padded
                                                  int* __restrict__ realcnt,  // NB
                                                  unsigned* __restrict__ ebuf,
                                                  int e, int nb,
                                                  const float4* __restrict__ xf,
                                                  unsigned short* __restrict__ xb,
                                                  long n8,
                                                  const float* __restrict__ w0a,
                                                  const float* __restrict__ w0b,
                                                  const float* __restrict__ w1a,
                                                  const float* __restrict__ w1b,
                                                  unsigned short* __restrict__ wT,
                                                  const int* __restrict__ roots,
                                                  int nr,
                                                  int* __restrict__ af_root) {
    __shared__ unsigned lbuf[NBINS * BCAP];   // 119.2 KB
    __shared__ int lcnt[NBINS];
    __shared__ int sbase[NBINS];
    const int t = threadIdx.x;
    for (int b = t; b < nb; b += 1024) lcnt[b] = 0;

    // --- root bitmap (first block's threads cover nr<=1024) ---
    {
        int gi = blockIdx.x * 1024 + t;
        if (gi < nr) af_root[roots[gi]] = 1;
    }
    // --- weight transpose: wT[m][n][k] = bf16(w_m[k][n]), 4x128x128 ---
    {
        int gi = blockIdx.x * 1024 + t;
        if (gi < 65536) {
            int m = gi >> 14, j = gi & 16383;
            const float* w = (m == 0) ? w0a : (m == 1) ? w0b : (m == 2) ? w1a : w1b;
            int k = j >> 7, n = j & 127;
            *(__bf16*)&wT[m * 16384 + n * 128 + k] = (__bf16)w[j];
        }
    }
    // --- x conversion: f32 -> bf16, node-major (grid-stride) ---
    for (long i = (long)blockIdx.x * 1024 + t; i < n8; i += 262144) {
        float4 a = xf[2 * i], b = xf[2 * i + 1];
        bf16x8 v;
        v[0] = (__bf16)a.x; v[1] = (__bf16)a.y; v[2] = (__bf16)a.z; v[3] = (__bf16)a.w;
        v[4] = (__bf16)b.x; v[5] = (__bf16)b.y; v[6] = (__bf16)b.z; v[7] = (__bf16)b.w;
        *(bf16x8*)&xb[i * 8] = v;
    }
    __syncthreads();

    const int per = (((e + 255) / 256) + 7) & ~7;   // 8-aligned slice, 256 blocks
    const int beg = blockIdx.x * per;
    const int end = (beg + per < e) ? beg + per : e;

    for (int base = beg; base < end; base += 8192) {
        int i0 = base + t * 8;
        if (i0 >= end) continue;
        if (i0 + 8 <= end) {
            int4 s0 = *(const int4*)&src[i0];
            int4 s1 = *(const int4*)&src[i0 + 4];
            int4 d0 = *(const int4*)&dst[i0];
            int4 d1 = *(const int4*)&dst[i0 + 4];
            int ss[8] = {s0.x, s0.y, s0.z, s0.w, s1.x, s1.y, s1.z, s1.w};
            int dd[8] = {d0.x, d0.y, d0.z, d0.w, d1.x, d1.y, d1.z, d1.w};
#pragma unroll
            for (int q = 0; q < 8; ++q) {
                int b = dd[q] >> 7;
                int p = atomicAdd(&lcnt[b], 1);
                if (p < BCAP)
                    lbuf[b * BCAP + p] =
                        (unsigned)ss[q] | ((unsigned)(dd[q] & 127) << 17);
            }
        } else {
            int lim = (i0 + 8 < end) ? i0 + 8 : end;
            for (int i = i0; i < lim; ++i) {
                int d = dst[i];
                int b = d >> 7;
                int p = atomicAdd(&lcnt[b], 1);
                if (p < BCAP)
                    lbuf[b * BCAP + p] =
                        (unsigned)src[i] | ((unsigned)(d & 127) << 17);
            }
        }
    }
    __syncthreads();

    // phase 1: reserve cell ranges
    for (int b = t; b < nb; b += 1024) {
        int r = lcnt[b]; if (r > BCAP) r = BCAP;
        int bb = 0;
        if (r > 0) {
            int nf = (r + 15) & ~15;
            bb = atomicAdd(&gcnt[b * 16], nf);
            atomicAdd(&realcnt[b], r);
        }
        sbase[b] = bb;
    }
    __syncthreads();

    // phase 2: cooperative full-line copies (16-lane group per bin, 64 groups)
    const int wave = t >> 6, lane = t & 63;
    const int gidx = wave * 4 + (lane >> 4), sub = lane & 15;
    for (int b = gidx; b < nb; b += 64) {
        int r = lcnt[b]; if (r > BCAP) r = BCAP;
        if (r == 0) continue;
        int nf = (r + 15) & ~15;
        int base2 = sbase[b];
        unsigned* cell = ebuf + (size_t)b * CAP;
        for (int j = sub; j < nf; j += 16) {
            unsigned v = (j < r) ? lbuf[b * BCAP + j] : 0xFFFFFFFFu;
            if (base2 + j < CAP) cell[base2 + j] = v;
        }
    }
}

// one block: exclusive scan of nb real bucket counts (nb <= 1024); rp[n]=e
__global__ __launch_bounds__(1024) void k_bscan(const int* __restrict__ realcnt,
                                                int* __restrict__ boff,
                                                int* __restrict__ rp,
                                                int nb, int n, int e) {
    __shared__ int sh[1024];
    int t = threadIdx.x;
    sh[t] = (t < nb) ? realcnt[t] : 0;
    __syncthreads();
    for (int off = 1; off < 1024; off <<= 1) {
        int u = (t >= off) ? sh[t - off] : 0;
        __syncthreads();
        sh[t] += u;
        __syncthreads();
    }
    if (t < nb) boff[t] = (t == 0) ? 0 : sh[t - 1];
    if (t == 0) rp[n] = e;
}

// one block per bucket: histogram (skip sentinels) -> scan -> rp -> csr.
// Also flags the active set inline: af[root]=1, af[src of root-edges]=1.
__global__ __launch_bounds__(512) void k_build(const unsigned* __restrict__ ebuf,
                                               const int* __restrict__ gcnt,
                                               const int* __restrict__ boff,
                                               int* __restrict__ rp,
                                               int* __restrict__ csr,
                                               const int* __restrict__ af_root,
                                               int* __restrict__ af, int n) {
    __shared__ int bins[128];
    __shared__ int incl[128];
    __shared__ int cur[128];
    __shared__ unsigned char isroot[128];
    int b = blockIdx.x, t = threadIdx.x;
    if (t < 128) {
        bins[t] = 0;
        int node = b * 128 + t;
        unsigned char ir = (node < n && af_root[node]) ? 1 : 0;
        isroot[t] = ir;
        if (ir) af[node] = 1;
    }
    __syncthreads();
    int c = gcnt[b * 16]; if (c > CAP) c = CAP;
    const unsigned* seg = ebuf + ((size_t)b * CAP);
    for (int j = t; j < c; j += 512) {
        unsigned w = seg[j];
        if (w != 0xFFFFFFFFu) atomicAdd(&bins[(w >> 17) & 127], 1);
    }
    __syncthreads();
    if (t < 128) incl[t] = bins[t];
    __syncthreads();
    for (int off = 1; off < 128; off <<= 1) {
        int u = (t < 128 && t >= off) ? incl[t - off] : 0;
        __syncthreads();
        if (t < 128) incl[t] += u;
        __syncthreads();
    }
    int base = boff[b];
    if (t < 128) {
        int ex = (t == 0) ? 0 : incl[t - 1];
        cur[t] = ex;
        int node = b * 128 + t;
        if (node < n) rp[node] = base + ex;
    }
    __syncthreads();
    for (int j = t; j < c; j += 512) {
        unsigned w = seg[j];
        if (w != 0xFFFFFFFFu) {
            int ldst = (w >> 17) & 127;
            int s = (int)(w & 0x1FFFF);
            int slot = atomicAdd(&cur[ldst], 1);
            csr[base + slot] = s;
            if (isroot[ldst]) af[s] = 1;   // flag root in-neighbor
        }
    }
}

__global__ void k_compact(const int* __restrict__ af, int* __restrict__ list,
                          int* __restrict__ cnt, int n) {
    int i = blockIdx.x * blockDim.x + threadIdx.x;
    if (i < n && af[i]) {
        int p = atomicAdd(cnt, 1);
        list[p] = i;
    }
}

// ---------------- segment sum fused with GIN update ----------------
// z[j] = (1+eps)*x[node] + sum_{s in N(node)} x[s]   (bf16 out, f32 accum)
// 16 lanes per output row; max-TLP standalone kernel (R9 lesson).
__global__ __launch_bounds__(256) void k_segz(const unsigned short* __restrict__ xb,
                                              const int* __restrict__ rp,
                                              const int* __restrict__ csr,
                                              const float* __restrict__ epsp,
                                              unsigned short* __restrict__ zout,
                                              const int* __restrict__ list,
                                              const int* __restrict__ cntp, int n) {
    int gid = blockIdx.x * 256 + threadIdx.x;
    int j = gid >> 4, lane = gid & 15;
    int rows = n;
    if (cntp) { int c = *cntp; rows = c < n ? c : n; }
    if (j >= rows) return;
    int node = list ? list[j] : j;
    int b = rp[node], e = rp[node + 1];
    float s0[8], s1[8];
#pragma unroll
    for (int q = 0; q < 8; ++q) { s0[q] = 0.f; s1[q] = 0.f; }
    int k = b;
    for (; k + 1 < e; k += 2) {
        bf16x8 v0 = *(const bf16x8*)&xb[(size_t)csr[k]     * 128 + lane * 8];
        bf16x8 v1 = *(const bf16x8*)&xb[(size_t)csr[k + 1] * 128 + lane * 8];
#pragma unroll
        for (int q = 0; q < 8; ++q) { s0[q] += (float)v0[q]; s1[q] += (float)v1[q]; }
    }
    if (k < e) {
        bf16x8 v0 = *(const bf16x8*)&xb[(size_t)csr[k] * 128 + lane * 8];
#pragma unroll
        for (int q = 0; q < 8; ++q) s0[q] += (float)v0[q];
    }
    const float epsv = 1.0f + epsp[0];
    bf16x8 xv = *(const bf16x8*)&xb[(size_t)node * 128 + lane * 8];
    bf16x8 o;
#pragma unroll
    for (int q = 0; q < 8; ++q)
        o[q] = (__bf16)(epsv * (float)xv[q] + s0[q] + s1[q]);
    *(bf16x8*)&zout[(size_t)j * 128 + lane * 8] = o;
}

// ---------------- MLP: out = relu( relu(z@w1+b1) @ w2 + b2 ) ----------------
// BM=128 rows/block, 256 threads = 4 waves in 2x2 over the 128x128 output.
// LDS = z/h/out tile only (34.8 KB); B read from global (L2-hot).
// Output routed through LDS -> bf16x8 global stores (full-line writes even
// when rows are list-scattered).
__global__ __launch_bounds__(256) void k_mlp(const unsigned short* __restrict__ zbuf,
                                             const unsigned short* __restrict__ w1T,
                                             const float* __restrict__ b1,
                                             const unsigned short* __restrict__ w2T,
                                             const float* __restrict__ b2,
                                             unsigned short* __restrict__ out,
                                             const int* __restrict__ list,
                                             const int* __restrict__ cntp, int nrows) {
    __shared__ unsigned short zt[128 * LDR];   // 34.8 KB
    const int t = threadIdx.x;
    int rows = nrows;
    if (cntp) { int c = *cntp; rows = c < nrows ? c : nrows; }
    const int row0 = blockIdx.x * 128;
    if (row0 >= rows) return;

    // stage z tile (coalesced from zbuf)
    for (int i = t; i < 2048; i += 256) {
        int r = i >> 4, c = i & 15;
        int g = row0 + r;
        bf16x8 zv;
        if (g < rows) {
            zv = *(const bf16x8*)&zbuf[(size_t)g * 128 + c * 8];
        } else {
#pragma unroll
            for (int q = 0; q < 8; ++q) zv[q] = (__bf16)0.0f;
        }
        *(bf16x8*)&zt[r * LDR + c * 8] = zv;
    }
    __syncthreads();

    const int lane = t & 63;
    const int wm = (t >> 7) & 1, wn = (t >> 6) & 1;
    const int lr = lane & 15, lk = lane >> 4;

    f32x4 zero4 = {0.f, 0.f, 0.f, 0.f};
    f32x4 acc[4][4];
#pragma unroll
    for (int mt = 0; mt < 4; ++mt)
#pragma unroll
        for (int nt = 0; nt < 4; ++nt) acc[mt][nt] = zero4;

    // -------- GEMM1: z @ w1 (B from global, L2-resident) --------
#pragma unroll
    for (int kb = 0; kb < 4; ++kb) {
        const int c = kb * 4 + lk;
        bf16x8 a[4];
#pragma unroll
        for (int mt = 0; mt < 4; ++mt)
            a[mt] = *(const bf16x8*)&zt[(wm * 64 + mt * 16 + lr) * LDR + c * 8];
#pragma unroll
        for (int nt = 0; nt < 4; ++nt) {
            bf16x8 b = *(const bf16x8*)&w1T[(wn * 64 + nt * 16 + lr) * 128 + c * 8];
#pragma unroll
            for (int mt = 0; mt < 4; ++mt)
                acc[mt][nt] = __builtin_amdgcn_mfma_f32_16x16x32_bf16(a[mt], b, acc[mt][nt], 0, 0, 0);
        }
    }
    __syncthreads();   // all zt reads done before in-place h overwrite

    // h = relu(acc + b1) -> zt (in place)
#pragma unroll
    for (int nt = 0; nt < 4; ++nt) {
        int col = wn * 64 + nt * 16 + lr;
        float bv = b1[col];
#pragma unroll
        for (int mt = 0; mt < 4; ++mt)
#pragma unroll
            for (int q = 0; q < 4; ++q) {
                int hr = wm * 64 + mt * 16 + lk * 4 + q;
                float hv = fmaxf(acc[mt][nt][q] + bv, 0.f);
                *(__bf16*)&zt[hr * LDR + col] = (__bf16)hv;
            }
    }
    __syncthreads();

    // -------- GEMM2: h @ w2 --------
    f32x4 acc2[4][4];
#pragma unroll
    for (int mt = 0; mt < 4; ++mt)
#pragma unroll
        for (int nt = 0; nt < 4; ++nt) acc2[mt][nt] = zero4;
#pragma unroll
    for (int kb = 0; kb < 4; ++kb) {
        const int c = kb * 4 + lk;
        bf16x8 a[4];
#pragma unroll
        for (int mt = 0; mt < 4; ++mt)
            a[mt] = *(const bf16x8*)&zt[(wm * 64 + mt * 16 + lr) * LDR + c * 8];
#pragma unroll
        for (int nt = 0; nt < 4; ++nt) {
            bf16x8 b = *(const bf16x8*)&w2T[(wn * 64 + nt * 16 + lr) * 128 + c * 8];
#pragma unroll
            for (int mt = 0; mt < 4; ++mt)
                acc2[mt][nt] = __builtin_amdgcn_mfma_f32_16x16x32_bf16(a[mt], b, acc2[mt][nt], 0, 0, 0);
        }
    }
    __syncthreads();   // all zt (h) reads done before out-tile overwrite

    // out-tile = relu(acc2 + b2) -> zt (in place)
#pragma unroll
    for (int nt = 0; nt < 4; ++nt) {
        int col = wn * 64 + nt * 16 + lr;
        float bv = b2[col];
#pragma unroll
        for (int mt = 0; mt < 4; ++mt)
#pragma unroll
            for (int q = 0; q < 4; ++q) {
                int orow = wm * 64 + mt * 16 + lk * 4 + q;
                float ov = fmaxf(acc2[mt][nt][q] + bv, 0.f);
                *(__bf16*)&zt[orow * LDR + col] = (__bf16)ov;
            }
    }
    __syncthreads();

    // vectorized global stores: one bf16x8 per 16B chunk, full-line rows
    for (int i = t; i < 2048; i += 256) {
        int r = i >> 4, c = i & 15;
        int g = row0 + r;
        if (g < rows) {
            int node = list ? list[g] : g;
            *(bf16x8*)&out[(size_t)node * 128 + c * 8] =
                *(const bf16x8*)&zt[r * LDR + c * 8];
        }
    }
}

// ---------------- layer 2 at roots only ----------------
__global__ __launch_bounds__(128) void k_root(const unsigned short* __restrict__ x2,
                                              const int* __restrict__ rp,
                                              const int* __restrict__ csr,
                                              const int* __restrict__ roots,
                                              const float* __restrict__ epsp,
                                              const float* __restrict__ wa,
                                              const float* __restrict__ ba,
                                              const float* __restrict__ wb,
                                              const float* __restrict__ bb,
                                              float* __restrict__ out) {
    __shared__ float hin[128];
    __shared__ float h[64];
    int r = blockIdx.x, t = threadIdx.x;
    int node = roots[r];
    float s = (1.0f + epsp[0]) * (float)(*(const __bf16*)&x2[(size_t)node * 128 + t]);
    int b = rp[node], e = rp[node + 1];
    for (int k = b; k < e; ++k)
        s += (float)(*(const __bf16*)&x2[(size_t)csr[k] * 128 + t]);
    hin[t] = s;
    __syncthreads();
    if (t < 64) {
        float a = ba[t];
        for (int k = 0; k < 128; ++k) a += hin[k] * wa[k * 64 + t];
        h[t] = fmaxf(a, 0.f);
    }
    __syncthreads();
    if (t < 64) {
        float a = bb[t];
        for (int k = 0; k < 64; ++k) a += h[k] * wb[k * 64 + t];
        out[(size_t)r * 64 + t] = a;
    }
}

extern "C" void kernel_launch(void* const* d_in, const int* in_sizes, int n_in,
                              void* d_out, int out_size, void* d_ws, size_t ws_size,
                              hipStream_t stream) {
    const float* x    = (const float*)d_in[0];
    const int*   ei   = (const int*)d_in[1];
    const int*   root = (const int*)d_in[2];
    const float* eps0 = (const float*)d_in[3];
    const float* w0a  = (const float*)d_in[4];
    const float* b0a  = (const float*)d_in[5];
    const float* w0b  = (const float*)d_in[6];
    const float* b0b  = (const float*)d_in[7];
    const float* eps1 = (const float*)d_in[8];
    const float* w1a  = (const float*)d_in[9];
    const float* b1a  = (const float*)d_in[10];
    const float* w1b  = (const float*)d_in[11];
    const float* b1b  = (const float*)d_in[12];
    const float* eps2 = (const float*)d_in[13];
    const float* w2a  = (const float*)d_in[14];
    const float* b2a  = (const float*)d_in[15];
    const float* w2b  = (const float*)d_in[16];
    const float* b2b  = (const float*)d_in[17];

    const int N  = in_sizes[0] / 128;
    const int E  = in_sizes[1] / 2;
    const int NR = in_sizes[2];
    const int MAXACT = 65536;
    const int NB = (N + 127) / 128;           // buckets of 128 nodes (782)
    const int* src = ei;
    const int* dst = ei + E;

    // ---- workspace layout ----
    char* p = (char*)d_ws;
    unsigned short* xb = (unsigned short*)p; p += (size_t)N * 128 * 2;        // 25.6 MB
    unsigned short* x1 = (unsigned short*)p; p += (size_t)N * 128 * 2;        // 25.6 MB
    unsigned short* z0 = (unsigned short*)p; p += (size_t)N * 128 * 2;        // 25.6 MB
    // shared region: ebuf (CSR build) then x2 (mlp1 output) — disjoint in time
    char* shared0 = p;
    size_t ebuf_bytes = (size_t)NB * CAP * 4;                                 // 25.6 MB
    size_t x2_bytes   = (size_t)N * 128 * 2;                                  // 25.6 MB
    p += (ebuf_bytes > x2_bytes ? ebuf_bytes : x2_bytes);
    unsigned*       ebuf = (unsigned*)shared0;
    unsigned short* x2   = (unsigned short*)shared0;
    unsigned short* z1   = (unsigned short*)p; p += (size_t)MAXACT * 128 * 2; // 16.8 MB
    unsigned short* wT   = (unsigned short*)p; p += 4 * 128 * 128 * 2;
    int* rp      = (int*)p; p += (size_t)(N + 64) * 4;
    int* list    = (int*)p; p += (size_t)(N + 64) * 4;
    int* boff    = (int*)p; p += 4096;
    // zeroed region (single memset): af | af_root | cnt | gcnt | realcnt
    char* zbeg = p;
    int* af      = (int*)p; p += (size_t)(N + 64) * 4;
    int* af_root = (int*)p; p += (size_t)(N + 64) * 4;
    int* cnt     = (int*)p; p += 256;
    int* gcnt    = (int*)p; p += (size_t)NB * 16 * 4;      // 64B-padded counters
    int* realcnt = (int*)p; p += (size_t)(NB + 64) * 4;
    size_t zbytes = (size_t)(p - zbeg);
    int* csr     = (int*)p; p += (size_t)E * 4;
    unsigned short* w0aT = wT;
    unsigned short* w0bT = wT + 16384;
    unsigned short* w1aT = wT + 32768;
    unsigned short* w1bT = wT + 49152;

    // ---- CSR build + conversions (merged) ----
    hipMemsetAsync(zbeg, 0, zbytes, stream);
    k_scatter<<<256, 1024, 0, stream>>>(src, dst, gcnt, realcnt, ebuf, E, NB,
                                        (const float4*)x, xb, (long)N * 16,
                                        w0a, w0b, w1a, w1b, wT,
                                        root, NR, af_root);
    k_bscan<<<1, 1024, 0, stream>>>(realcnt, boff, rp, NB, N, E);
    k_build<<<NB, 512, 0, stream>>>(ebuf, gcnt, boff, rp, csr, af_root, af, N);
    k_compact<<<(N + 255) / 256, 256, 0, stream>>>(af, list, cnt, N);

    // ---- layer 0 (all nodes) ----
    k_segz<<<(N * 16 + 255) / 256, 256, 0, stream>>>(xb, rp, csr, eps0, z0,
                                                     nullptr, nullptr, N);
    k_mlp<<<(N + 127) / 128, 256, 0, stream>>>(z0, w0aT, b0a, w0bT, b0b,
                                               x1, nullptr, nullptr, N);
    // ---- layer 1 (active set only) ----
    k_segz<<<(MAXACT * 16 + 255) / 256, 256, 0, stream>>>(x1, rp, csr, eps1, z1,
                                                          list, cnt, MAXACT);
    k_mlp<<<(MAXACT + 127) / 128, 256, 0, stream>>>(z1, w1aT, b1a, w1bT, b1b,
                                                    x2, list, cnt, MAXACT);
    // ---- layer 2 (roots only) ----
    k_root<<<NR, 128, 0, stream>>>(x2, rp, csr, root, eps2, w2a, b2a, w2b, b2b,
                                   (float*)d_out);
}

// Round 15
// 209.910 us; speedup vs baseline: 1.5340x; 1.0143x over previous
//
#include <hip/hip_runtime.h>

// ---------------------------------------------------------------------------
// GIN 3-layer forward on MI355X (gfx950).
//   - features/weights bf16 node-major (f32 accumulate). Node-major 256B rows
//     gather at ~7 TB/s logical = practical random-gather ceiling (R12-R14).
//   - k_scatter (merged): LDS-binned edge scatter with FULL-LINE flushes
//     (sentinel-padded 64B bursts; this chip's L2 does NOT merge scattered
//     partial-line stores) + x f32->bf16 conversion + weight transpose +
//     root bitmap, all hidden under the latency-bound binning.
//   - k_build (merged): per-bucket histogram -> scan -> rp -> csr slotting,
//     flags root in-neighbors inline (af) via af_root bitmap.
//   - k_gmlp (R15): gather + GIN update + BOTH MLP GEMMs in ONE kernel,
//     PRESERVING segz's thread mapping (16 rows x 16 lanes per 256-thread
//     block, 6250 blocks, tiny LDS, launch_bounds(256,6)) -- R9's fusion
//     failed because it destroyed gather TLP (782 blocks, 8 rows/thread
//     serial); this keeps max TLP and adds 16 MFMAs/wave after the gather.
//     Kills the z round-trip (102 MB) and two launches.
//   - layer 1 only on active set = roots U in-neighbors(roots); layer 2 only
//     at the 1024 roots.
//   NOTE: edge packing assumes N <= 2^17; bins assume N <= 100352.
// ---------------------------------------------------------------------------

typedef __bf16  bf16x8 __attribute__((ext_vector_type(8)));
typedef float   f32x4  __attribute__((ext_vector_type(4)));

#define NBINS 784     // >= (N+127)/128
#define BCAP  38      // words per LDS bin (per-bin lambda ~8)
#define CAP   8192    // words per global bucket cell (real ~2048 + pads)
#define LDR   136     // LDS row stride in shorts (+8 pad)

// ---------------- merged scatter + conversions + root flag ----------------
// 256 blocks x 1024 threads (16 waves/CU): binning is LDS-atomic latency
// bound; the streaming conversions hide under it.
__global__ __launch_bounds__(1024) void k_scatter(const int* __restrict__ src,
                                                  const int* __restrict__ dst,
                                                  int* __restrict__ gcnt,     // NB*16 padded
                                                  int* __restrict__ realcnt,  // NB
                                                  unsigned* __restrict__ ebuf,
                                                  int e, int nb,
                                                  const float4* __restrict__ xf,
                                                  unsigned short* __restrict__ xb,
                                                  long n8,
                                                  const float* __restrict__ w0a,
                                                  const float* __restrict__ w0b,
                                                  const float* __restrict__ w1a,
                                                  const float* __restrict__ w1b,
                                                  unsigned short* __restrict__ wT,
                                                  const int* __restrict__ roots,
                                                  int nr,
                                                  int* __restrict__ af_root) {
    __shared__ unsigned lbuf[NBINS * BCAP];   // 119.2 KB
    __shared__ int lcnt[NBINS];
    __shared__ int sbase[NBINS];
    const int t = threadIdx.x;
    for (int b = t; b < nb; b += 1024) lcnt[b] = 0;

    // --- root bitmap ---
    {
        int gi = blockIdx.x * 1024 + t;
        if (gi < nr) af_root[roots[gi]] = 1;
    }
    // --- weight transpose: wT[m][n][k] = bf16(w_m[k][n]), 4x128x128 ---
    {
        int gi = blockIdx.x * 1024 + t;
        if (gi < 65536) {
            int m = gi >> 14, j = gi & 16383;
            const float* w = (m == 0) ? w0a : (m == 1) ? w0b : (m == 2) ? w1a : w1b;
            int k = j >> 7, n = j & 127;
            *(__bf16*)&wT[m * 16384 + n * 128 + k] = (__bf16)w[j];
        }
    }
    // --- x conversion: f32 -> bf16, node-major (grid-stride) ---
    for (long i = (long)blockIdx.x * 1024 + t; i < n8; i += 262144) {
        float4 a = xf[2 * i], b = xf[2 * i + 1];
        bf16x8 v;
        v[0] = (__bf16)a.x; v[1] = (__bf16)a.y; v[2] = (__bf16)a.z; v[3] = (__bf16)a.w;
        v[4] = (__bf16)b.x; v[5] = (__bf16)b.y; v[6] = (__bf16)b.z; v[7] = (__bf16)b.w;
        *(bf16x8*)&xb[i * 8] = v;
    }
    __syncthreads();

    const int per = (((e + 255) / 256) + 7) & ~7;   // 8-aligned slice, 256 blocks
    const int beg = blockIdx.x * per;
    const int end = (beg + per < e) ? beg + per : e;

    for (int base = beg; base < end; base += 8192) {
        int i0 = base + t * 8;
        if (i0 >= end) continue;
        if (i0 + 8 <= end) {
            int4 s0 = *(const int4*)&src[i0];
            int4 s1 = *(const int4*)&src[i0 + 4];
            int4 d0 = *(const int4*)&dst[i0];
            int4 d1 = *(const int4*)&dst[i0 + 4];
            int ss[8] = {s0.x, s0.y, s0.z, s0.w, s1.x, s1.y, s1.z, s1.w};
            int dd[8] = {d0.x, d0.y, d0.z, d0.w, d1.x, d1.y, d1.z, d1.w};
#pragma unroll
            for (int q = 0; q < 8; ++q) {
                int b = dd[q] >> 7;
                int p = atomicAdd(&lcnt[b], 1);
                if (p < BCAP)
                    lbuf[b * BCAP + p] =
                        (unsigned)ss[q] | ((unsigned)(dd[q] & 127) << 17);
            }
        } else {
            int lim = (i0 + 8 < end) ? i0 + 8 : end;
            for (int i = i0; i < lim; ++i) {
                int d = dst[i];
                int b = d >> 7;
                int p = atomicAdd(&lcnt[b], 1);
                if (p < BCAP)
                    lbuf[b * BCAP + p] =
                        (unsigned)src[i] | ((unsigned)(d & 127) << 17);
            }
        }
    }
    __syncthreads();

    // phase 1: reserve cell ranges
    for (int b = t; b < nb; b += 1024) {
        int r = lcnt[b]; if (r > BCAP) r = BCAP;
        int bb = 0;
        if (r > 0) {
            int nf = (r + 15) & ~15;
            bb = atomicAdd(&gcnt[b * 16], nf);
            atomicAdd(&realcnt[b], r);
        }
        sbase[b] = bb;
    }
    __syncthreads();

    // phase 2: cooperative full-line copies (16-lane group per bin, 64 groups)
    const int wave = t >> 6, lane = t & 63;
    const int gidx = wave * 4 + (lane >> 4), sub = lane & 15;
    for (int b = gidx; b < nb; b += 64) {
        int r = lcnt[b]; if (r > BCAP) r = BCAP;
        if (r == 0) continue;
        int nf = (r + 15) & ~15;
        int base2 = sbase[b];
        unsigned* cell = ebuf + (size_t)b * CAP;
        for (int j = sub; j < nf; j += 16) {
            unsigned v = (j < r) ? lbuf[b * BCAP + j] : 0xFFFFFFFFu;
            if (base2 + j < CAP) cell[base2 + j] = v;
        }
    }
}

// one block: exclusive scan of nb real bucket counts (nb <= 1024); rp[n]=e
__global__ __launch_bounds__(1024) void k_bscan(const int* __restrict__ realcnt,
                                                int* __restrict__ boff,
                                                int* __restrict__ rp,
                                                int nb, int n, int e) {
    __shared__ int sh[1024];
    int t = threadIdx.x;
    sh[t] = (t < nb) ? realcnt[t] : 0;
    __syncthreads();
    for (int off = 1; off < 1024; off <<= 1) {
        int u = (t >= off) ? sh[t - off] : 0;
        __syncthreads();
        sh[t] += u;
        __syncthreads();
    }
    if (t < nb) boff[t] = (t == 0) ? 0 : sh[t - 1];
    if (t == 0) rp[n] = e;
}

// one block per bucket: histogram (skip sentinels) -> scan -> rp -> csr.
// Also flags the active set inline: af[root]=1, af[src of root-edges]=1.
__global__ __launch_bounds__(512) void k_build(const unsigned* __restrict__ ebuf,
                                               const int* __restrict__ gcnt,
                                               const int* __restrict__ boff,
                                               int* __restrict__ rp,
                                               int* __restrict__ csr,
                                               const int* __restrict__ af_root,
                                               int* __restrict__ af, int n) {
    __shared__ int bins[128];
    __shared__ int incl[128];
    __shared__ int cur[128];
    __shared__ unsigned char isroot[128];
    int b = blockIdx.x, t = threadIdx.x;
    if (t < 128) {
        bins[t] = 0;
        int node = b * 128 + t;
        unsigned char ir = (node < n && af_root[node]) ? 1 : 0;
        isroot[t] = ir;
        if (ir) af[node] = 1;
    }
    __syncthreads();
    int c = gcnt[b * 16]; if (c > CAP) c = CAP;
    const unsigned* seg = ebuf + ((size_t)b * CAP);
    for (int j = t; j < c; j += 512) {
        unsigned w = seg[j];
        if (w != 0xFFFFFFFFu) atomicAdd(&bins[(w >> 17) & 127], 1);
    }
    __syncthreads();
    if (t < 128) incl[t] = bins[t];
    __syncthreads();
    for (int off = 1; off < 128; off <<= 1) {
        int u = (t < 128 && t >= off) ? incl[t - off] : 0;
        __syncthreads();
        if (t < 128) incl[t] += u;
        __syncthreads();
    }
    int base = boff[b];
    if (t < 128) {
        int ex = (t == 0) ? 0 : incl[t - 1];
        cur[t] = ex;
        int node = b * 128 + t;
        if (node < n) rp[node] = base + ex;
    }
    __syncthreads();
    for (int j = t; j < c; j += 512) {
        unsigned w = seg[j];
        if (w != 0xFFFFFFFFu) {
            int ldst = (w >> 17) & 127;
            int s = (int)(w & 0x1FFFF);
            int slot = atomicAdd(&cur[ldst], 1);
            csr[base + slot] = s;
            if (isroot[ldst]) af[s] = 1;   // flag root in-neighbor
        }
    }
}

__global__ void k_compact(const int* __restrict__ af, int* __restrict__ list,
                          int* __restrict__ cnt, int n) {
    int i = blockIdx.x * blockDim.x + threadIdx.x;
    if (i < n && af[i]) {
        int p = atomicAdd(cnt, 1);
        list[p] = i;
    }
}

// ---------------- fused gather + GIN update + 2-GEMM MLP ----------------
// Block = 16 output rows, 256 threads.
//   phase 1 (gather): EXACT segz mapping - thread (r16,lane16) accumulates
//     z[row r16][cols lane16*8..+7] over the row's edges; max TLP preserved
//     (6250 blocks, ~6 blocks/CU via launch_bounds(256,6), 8.7KB LDS).
//   phase 2: 4 waves x (16x32 output slice) x 2 GEMMs, MFMA 16x16x32,
//     B-fragments streamed from L2-resident w1T/w2T (same verified algebra
//     as the previous k_mlp with wm=mt=0).
//   out rows written via LDS -> bf16x8 full-line stores.
__global__ __launch_bounds__(256, 6) void k_gmlp(const unsigned short* __restrict__ xb,
                                                 const int* __restrict__ rp,
                                                 const int* __restrict__ csr,
                                                 const float* __restrict__ epsp,
                                                 const unsigned short* __restrict__ w1T,
                                                 const float* __restrict__ b1,
                                                 const unsigned short* __restrict__ w2T,
                                                 const float* __restrict__ b2,
                                                 unsigned short* __restrict__ out,
                                                 const int* __restrict__ list,
                                                 const int* __restrict__ cntp, int nrows) {
    __shared__ unsigned short zt[16 * LDR];   // 4.35 KB (z, then out-tile)
    __shared__ unsigned short ht[16 * LDR];   // 4.35 KB
    const int t = threadIdx.x;
    int rows = nrows;
    if (cntp) { int c = *cntp; rows = c < nrows ? c : nrows; }
    const int row0 = blockIdx.x * 16;
    if (row0 >= rows) return;

    // ---- phase 1: gather z = (1+eps)*x[node] + sum_{s in N} x[s] ----
    {
        const int r16 = t >> 4, lane16 = t & 15;
        int j = row0 + r16;
        bf16x8 zv;
        if (j < rows) {
            int node = list ? list[j] : j;
            int b = rp[node], e = rp[node + 1];
            float s[8];
#pragma unroll
            for (int q = 0; q < 8; ++q) s[q] = 0.f;
            int k = b;
            for (; k + 1 < e; k += 2) {
                bf16x8 v0 = *(const bf16x8*)&xb[(size_t)csr[k]     * 128 + lane16 * 8];
                bf16x8 v1 = *(const bf16x8*)&xb[(size_t)csr[k + 1] * 128 + lane16 * 8];
#pragma unroll
                for (int q = 0; q < 8; ++q) s[q] += (float)v0[q] + (float)v1[q];
            }
            if (k < e) {
                bf16x8 v0 = *(const bf16x8*)&xb[(size_t)csr[k] * 128 + lane16 * 8];
#pragma unroll
                for (int q = 0; q < 8; ++q) s[q] += (float)v0[q];
            }
            const float epsv = 1.0f + epsp[0];
            bf16x8 xv = *(const bf16x8*)&xb[(size_t)node * 128 + lane16 * 8];
#pragma unroll
            for (int q = 0; q < 8; ++q)
                zv[q] = (__bf16)(epsv * (float)xv[q] + s[q]);
        } else {
#pragma unroll
            for (int q = 0; q < 8; ++q) zv[q] = (__bf16)0.0f;
        }
        *(bf16x8*)&zt[(t >> 4) * LDR + (t & 15) * 8] = zv;
    }
    __syncthreads();

    // ---- phase 2: two GEMMs, wave = 32-col slice ----
    const int lane = t & 63;
    const int wave = t >> 6;
    const int lr = lane & 15, lk = lane >> 4;
    const int n0 = wave * 32;

    f32x4 zero4 = {0.f, 0.f, 0.f, 0.f};
    f32x4 acc[2] = {zero4, zero4};
#pragma unroll
    for (int kb = 0; kb < 4; ++kb) {
        bf16x8 a = *(const bf16x8*)&zt[lr * LDR + (kb * 4 + lk) * 8];
#pragma unroll
        for (int nt = 0; nt < 2; ++nt) {
            bf16x8 b = *(const bf16x8*)&w1T[(size_t)(n0 + nt * 16 + lr) * 128 + (kb * 4 + lk) * 8];
            acc[nt] = __builtin_amdgcn_mfma_f32_16x16x32_bf16(a, b, acc[nt], 0, 0, 0);
        }
    }
    // h = relu(acc + b1) -> ht
#pragma unroll
    for (int nt = 0; nt < 2; ++nt) {
        int col = n0 + nt * 16 + lr;
        float bv = b1[col];
#pragma unroll
        for (int q = 0; q < 4; ++q) {
            float hv = fmaxf(acc[nt][q] + bv, 0.f);
            *(__bf16*)&ht[(lk * 4 + q) * LDR + col] = (__bf16)hv;
        }
    }
    __syncthreads();

    f32x4 acc2[2] = {zero4, zero4};
#pragma unroll
    for (int kb = 0; kb < 4; ++kb) {
        bf16x8 a = *(const bf16x8*)&ht[lr * LDR + (kb * 4 + lk) * 8];
#pragma unroll
        for (int nt = 0; nt < 2; ++nt) {
            bf16x8 b = *(const bf16x8*)&w2T[(size_t)(n0 + nt * 16 + lr) * 128 + (kb * 4 + lk) * 8];
            acc2[nt] = __builtin_amdgcn_mfma_f32_16x16x32_bf16(a, b, acc2[nt], 0, 0, 0);
        }
    }
    // out-tile = relu(acc2 + b2) -> zt (zt free after bar2)
#pragma unroll
    for (int nt = 0; nt < 2; ++nt) {
        int col = n0 + nt * 16 + lr;
        float bv = b2[col];
#pragma unroll
        for (int q = 0; q < 4; ++q) {
            float ov = fmaxf(acc2[nt][q] + bv, 0.f);
            *(__bf16*)&zt[(lk * 4 + q) * LDR + col] = (__bf16)ov;
        }
    }
    __syncthreads();

    // full-line stores: 256 threads x one 16B chunk (16 rows x 16 chunks)
    {
        int r = t >> 4, c = t & 15;
        int g = row0 + r;
        if (g < rows) {
            int node = list ? list[g] : g;
            *(bf16x8*)&out[(size_t)node * 128 + c * 8] =
                *(const bf16x8*)&zt[r * LDR + c * 8];
        }
    }
}

// ---------------- layer 2 at roots only ----------------
__global__ __launch_bounds__(128) void k_root(const unsigned short* __restrict__ x2,
                                              const int* __restrict__ rp,
                                              const int* __restrict__ csr,
                                              const int* __restrict__ roots,
                                              const float* __restrict__ epsp,
                                              const float* __restrict__ wa,
                                              const float* __restrict__ ba,
                                              const float* __restrict__ wb,
                                              const float* __restrict__ bb,
                                              float* __restrict__ out) {
    __shared__ float hin[128];
    __shared__ float h[64];
    int r = blockIdx.x, t = threadIdx.x;
    int node = roots[r];
    float s = (1.0f + epsp[0]) * (float)(*(const __bf16*)&x2[(size_t)node * 128 + t]);
    int b = rp[node], e = rp[node + 1];
    for (int k = b; k < e; ++k)
        s += (float)(*(const __bf16*)&x2[(size_t)csr[k] * 128 + t]);
    hin[t] = s;
    __syncthreads();
    if (t < 64) {
        float a = ba[t];
        for (int k = 0; k < 128; ++k) a += hin[k] * wa[k * 64 + t];
        h[t] = fmaxf(a, 0.f);
    }
    __syncthreads();
    if (t < 64) {
        float a = bb[t];
        for (int k = 0; k < 64; ++k) a += h[k] * wb[k * 64 + t];
        out[(size_t)r * 64 + t] = a;
    }
}

extern "C" void kernel_launch(void* const* d_in, const int* in_sizes, int n_in,
                              void* d_out, int out_size, void* d_ws, size_t ws_size,
                              hipStream_t stream) {
    const float* x    = (const float*)d_in[0];
    const int*   ei   = (const int*)d_in[1];
    const int*   root = (const int*)d_in[2];
    const float* eps0 = (const float*)d_in[3];
    const float* w0a  = (const float*)d_in[4];
    const float* b0a  = (const float*)d_in[5];
    const float* w0b  = (const float*)d_in[6];
    const float* b0b  = (const float*)d_in[7];
    const float* eps1 = (const float*)d_in[8];
    const float* w1a  = (const float*)d_in[9];
    const float* b1a  = (const float*)d_in[10];
    const float* w1b  = (const float*)d_in[11];
    const float* b1b  = (const float*)d_in[12];
    const float* eps2 = (const float*)d_in[13];
    const float* w2a  = (const float*)d_in[14];
    const float* b2a  = (const float*)d_in[15];
    const float* w2b  = (const float*)d_in[16];
    const float* b2b  = (const float*)d_in[17];

    const int N  = in_sizes[0] / 128;
    const int E  = in_sizes[1] / 2;
    const int NR = in_sizes[2];
    const int MAXACT = 65536;
    const int NB = (N + 127) / 128;           // buckets of 128 nodes (782)
    const int* src = ei;
    const int* dst = ei + E;

    // ---- workspace layout ----
    char* p = (char*)d_ws;
    unsigned short* xb = (unsigned short*)p; p += (size_t)N * 128 * 2;        // 25.6 MB
    unsigned short* x1 = (unsigned short*)p; p += (size_t)N * 128 * 2;        // 25.6 MB
    // shared region: ebuf (CSR build) then x2 (layer-1 output) — disjoint
    char* shared0 = p;
    size_t ebuf_bytes = (size_t)NB * CAP * 4;                                 // 25.6 MB
    size_t x2_bytes   = (size_t)N * 128 * 2;                                  // 25.6 MB
    p += (ebuf_bytes > x2_bytes ? ebuf_bytes : x2_bytes);
    unsigned*       ebuf = (unsigned*)shared0;
    unsigned short* x2   = (unsigned short*)shared0;
    unsigned short* wT   = (unsigned short*)p; p += 4 * 128 * 128 * 2;
    int* rp      = (int*)p; p += (size_t)(N + 64) * 4;
    int* list    = (int*)p; p += (size_t)(N + 64) * 4;
    int* boff    = (int*)p; p += 4096;
    // zeroed region (single memset): af | af_root | cnt | gcnt | realcnt
    char* zbeg = p;
    int* af      = (int*)p; p += (size_t)(N + 64) * 4;
    int* af_root = (int*)p; p += (size_t)(N + 64) * 4;
    int* cnt     = (int*)p; p += 256;
    int* gcnt    = (int*)p; p += (size_t)NB * 16 * 4;      // 64B-padded counters
    int* realcnt = (int*)p; p += (size_t)(NB + 64) * 4;
    size_t zbytes = (size_t)(p - zbeg);
    int* csr     = (int*)p; p += (size_t)E * 4;
    unsigned short* w0aT = wT;
    unsigned short* w0bT = wT + 16384;
    unsigned short* w1aT = wT + 32768;
    unsigned short* w1bT = wT + 49152;

    // ---- CSR build + conversions (merged) ----
    hipMemsetAsync(zbeg, 0, zbytes, stream);
    k_scatter<<<256, 1024, 0, stream>>>(src, dst, gcnt, realcnt, ebuf, E, NB,
                                        (const float4*)x, xb, (long)N * 16,
                                        w0a, w0b, w1a, w1b, wT,
                                        root, NR, af_root);
    k_bscan<<<1, 1024, 0, stream>>>(realcnt, boff, rp, NB, N, E);
    k_build<<<NB, 512, 0, stream>>>(ebuf, gcnt, boff, rp, csr, af_root, af, N);
    k_compact<<<(N + 255) / 256, 256, 0, stream>>>(af, list, cnt, N);

    // ---- layer 0 (all nodes, fused gather+MLP, max-TLP blocks) ----
    k_gmlp<<<(N + 15) / 16, 256, 0, stream>>>(xb, rp, csr, eps0,
                                              w0aT, b0a, w0bT, b0b,
                                              x1, nullptr, nullptr, N);
    // ---- layer 1 (active set only) ----
    k_gmlp<<<(MAXACT + 15) / 16, 256, 0, stream>>>(x1, rp, csr, eps1,
                                                   w1aT, b1a, w1bT, b1b,
                                                   x2, list, cnt, MAXACT);
    // ---- layer 2 (roots only) ----
    k_root<<<NR, 128, 0, stream>>>(x2, rp, csr, root, eps2, w2a, b2a, w2b, b2b,
                                   (float*)d_out);
}

// Round 16
// 203.230 us; speedup vs baseline: 1.5844x; 1.0329x over previous
//
#include <hip/hip_runtime.h>

// ---------------------------------------------------------------------------
// GIN 3-layer forward on MI355X (gfx950).
//   - features/weights bf16 node-major (f32 accumulate). Node-major 256B rows
//     gather at ~7 TB/s logical = practical random-gather ceiling (R12-R14).
//   - k_scatter (merged): LDS-binned edge scatter with FULL-LINE flushes
//     (sentinel-padded 64B bursts; this chip's L2 does NOT merge scattered
//     partial-line stores) + x f32->bf16 conversion + weight transpose +
//     root bitmap, all hidden under the latency-bound binning.
//   - k_build (merged): per-bucket histogram -> scan -> rp -> csr slotting,
//     flags root in-neighbors inline (af) via af_root bitmap.
//   - HYBRID layering (R16): layer 0 = separate k_segz (max-TLP gather, no
//     barrier coupling -> fabric ceiling) + k_mlp (128-row MFMA tile).
//     R15 lesson: fusing them couples 16 gather rows behind a barrier
//     (block time = max of 16 degrees ~ 1.6x mean) -> 101us vs 92us split.
//     Layer 1 (17K rows) keeps the fused k_gmlp: imbalance tax ~3us < the
//     launch + z-roundtrip it saves.
//   - layer 2 only at the 1024 roots.
//   NOTE: edge packing assumes N <= 2^17; bins assume N <= 100352.
// ---------------------------------------------------------------------------

typedef __bf16  bf16x8 __attribute__((ext_vector_type(8)));
typedef float   f32x4  __attribute__((ext_vector_type(4)));

#define NBINS 784     // >= (N+127)/128
#define BCAP  38      // words per LDS bin (per-bin lambda ~8)
#define CAP   8192    // words per global bucket cell (real ~2048 + pads)
#define LDR   136     // LDS row stride in shorts (+8 pad)

// ---------------- merged scatter + conversions + root flag ----------------
__global__ __launch_bounds__(1024) void k_scatter(const int* __restrict__ src,
                                                  const int* __restrict__ dst,
                                                  int* __restrict__ gcnt,     // NB*16 padded
                                                  int* __restrict__ realcnt,  // NB
                                                  unsigned* __restrict__ ebuf,
                                                  int e, int nb,
                                                  const float4* __restrict__ xf,
                                                  unsigned short* __restrict__ xb,
                                                  long n8,
                                                  const float* __restrict__ w0a,
                                                  const float* __restrict__ w0b,
                                                  const float* __restrict__ w1a,
                                                  const float* __restrict__ w1b,
                                                  unsigned short* __restrict__ wT,
                                                  const int* __restrict__ roots,
                                                  int nr,
                                                  int* __restrict__ af_root) {
    __shared__ unsigned lbuf[NBINS * BCAP];   // 119.2 KB
    __shared__ int lcnt[NBINS];
    __shared__ int sbase[NBINS];
    const int t = threadIdx.x;
    for (int b = t; b < nb; b += 1024) lcnt[b] = 0;

    {
        int gi = blockIdx.x * 1024 + t;
        if (gi < nr) af_root[roots[gi]] = 1;
    }
    {
        int gi = blockIdx.x * 1024 + t;
        if (gi < 65536) {
            int m = gi >> 14, j = gi & 16383;
            const float* w = (m == 0) ? w0a : (m == 1) ? w0b : (m == 2) ? w1a : w1b;
            int k = j >> 7, n = j & 127;
            *(__bf16*)&wT[m * 16384 + n * 128 + k] = (__bf16)w[j];
        }
    }
    for (long i = (long)blockIdx.x * 1024 + t; i < n8; i += 262144) {
        float4 a = xf[2 * i], b = xf[2 * i + 1];
        bf16x8 v;
        v[0] = (__bf16)a.x; v[1] = (__bf16)a.y; v[2] = (__bf16)a.z; v[3] = (__bf16)a.w;
        v[4] = (__bf16)b.x; v[5] = (__bf16)b.y; v[6] = (__bf16)b.z; v[7] = (__bf16)b.w;
        *(bf16x8*)&xb[i * 8] = v;
    }
    __syncthreads();

    const int per = (((e + 255) / 256) + 7) & ~7;   // 8-aligned slice, 256 blocks
    const int beg = blockIdx.x * per;
    const int end = (beg + per < e) ? beg + per : e;

    for (int base = beg; base < end; base += 8192) {
        int i0 = base + t * 8;
        if (i0 >= end) continue;
        if (i0 + 8 <= end) {
            int4 s0 = *(const int4*)&src[i0];
            int4 s1 = *(const int4*)&src[i0 + 4];
            int4 d0 = *(const int4*)&dst[i0];
            int4 d1 = *(const int4*)&dst[i0 + 4];
            int ss[8] = {s0.x, s0.y, s0.z, s0.w, s1.x, s1.y, s1.z, s1.w};
            int dd[8] = {d0.x, d0.y, d0.z, d0.w, d1.x, d1.y, d1.z, d1.w};
#pragma unroll
            for (int q = 0; q < 8; ++q) {
                int b = dd[q] >> 7;
                int p = atomicAdd(&lcnt[b], 1);
                if (p < BCAP)
                    lbuf[b * BCAP + p] =
                        (unsigned)ss[q] | ((unsigned)(dd[q] & 127) << 17);
            }
        } else {
            int lim = (i0 + 8 < end) ? i0 + 8 : end;
            for (int i = i0; i < lim; ++i) {
                int d = dst[i];
                int b = d >> 7;
                int p = atomicAdd(&lcnt[b], 1);
                if (p < BCAP)
                    lbuf[b * BCAP + p] =
                        (unsigned)src[i] | ((unsigned)(d & 127) << 17);
            }
        }
    }
    __syncthreads();

    for (int b = t; b < nb; b += 1024) {
        int r = lcnt[b]; if (r > BCAP) r = BCAP;
        int bb = 0;
        if (r > 0) {
            int nf = (r + 15) & ~15;
            bb = atomicAdd(&gcnt[b * 16], nf);
            atomicAdd(&realcnt[b], r);
        }
        sbase[b] = bb;
    }
    __syncthreads();

    const int wave = t >> 6, lane = t & 63;
    const int gidx = wave * 4 + (lane >> 4), sub = lane & 15;
    for (int b = gidx; b < nb; b += 64) {
        int r = lcnt[b]; if (r > BCAP) r = BCAP;
        if (r == 0) continue;
        int nf = (r + 15) & ~15;
        int base2 = sbase[b];
        unsigned* cell = ebuf + (size_t)b * CAP;
        for (int j = sub; j < nf; j += 16) {
            unsigned v = (j < r) ? lbuf[b * BCAP + j] : 0xFFFFFFFFu;
            if (base2 + j < CAP) cell[base2 + j] = v;
        }
    }
}

__global__ __launch_bounds__(1024) void k_bscan(const int* __restrict__ realcnt,
                                                int* __restrict__ boff,
                                                int* __restrict__ rp,
                                                int nb, int n, int e) {
    __shared__ int sh[1024];
    int t = threadIdx.x;
    sh[t] = (t < nb) ? realcnt[t] : 0;
    __syncthreads();
    for (int off = 1; off < 1024; off <<= 1) {
        int u = (t >= off) ? sh[t - off] : 0;
        __syncthreads();
        sh[t] += u;
        __syncthreads();
    }
    if (t < nb) boff[t] = (t == 0) ? 0 : sh[t - 1];
    if (t == 0) rp[n] = e;
}

__global__ __launch_bounds__(512) void k_build(const unsigned* __restrict__ ebuf,
                                               const int* __restrict__ gcnt,
                                               const int* __restrict__ boff,
                                               int* __restrict__ rp,
                                               int* __restrict__ csr,
                                               const int* __restrict__ af_root,
                                               int* __restrict__ af, int n) {
    __shared__ int bins[128];
    __shared__ int incl[128];
    __shared__ int cur[128];
    __shared__ unsigned char isroot[128];
    int b = blockIdx.x, t = threadIdx.x;
    if (t < 128) {
        bins[t] = 0;
        int node = b * 128 + t;
        unsigned char ir = (node < n && af_root[node]) ? 1 : 0;
        isroot[t] = ir;
        if (ir) af[node] = 1;
    }
    __syncthreads();
    int c = gcnt[b * 16]; if (c > CAP) c = CAP;
    const unsigned* seg = ebuf + ((size_t)b * CAP);
    for (int j = t; j < c; j += 512) {
        unsigned w = seg[j];
        if (w != 0xFFFFFFFFu) atomicAdd(&bins[(w >> 17) & 127], 1);
    }
    __syncthreads();
    if (t < 128) incl[t] = bins[t];
    __syncthreads();
    for (int off = 1; off < 128; off <<= 1) {
        int u = (t < 128 && t >= off) ? incl[t - off] : 0;
        __syncthreads();
        if (t < 128) incl[t] += u;
        __syncthreads();
    }
    int base = boff[b];
    if (t < 128) {
        int ex = (t == 0) ? 0 : incl[t - 1];
        cur[t] = ex;
        int node = b * 128 + t;
        if (node < n) rp[node] = base + ex;
    }
    __syncthreads();
    for (int j = t; j < c; j += 512) {
        unsigned w = seg[j];
        if (w != 0xFFFFFFFFu) {
            int ldst = (w >> 17) & 127;
            int s = (int)(w & 0x1FFFF);
            int slot = atomicAdd(&cur[ldst], 1);
            csr[base + slot] = s;
            if (isroot[ldst]) af[s] = 1;
        }
    }
}

__global__ void k_compact(const int* __restrict__ af, int* __restrict__ list,
                          int* __restrict__ cnt, int n) {
    int i = blockIdx.x * blockDim.x + threadIdx.x;
    if (i < n && af[i]) {
        int p = atomicAdd(cnt, 1);
        list[p] = i;
    }
}

// ---------------- segment sum fused with GIN update (layer 0) ------------
// z[j] = (1+eps)*x[node] + sum_{s in N(node)} x[s]; 16 lanes/row, max TLP.
__global__ __launch_bounds__(256) void k_segz(const unsigned short* __restrict__ xb,
                                              const int* __restrict__ rp,
                                              const int* __restrict__ csr,
                                              const float* __restrict__ epsp,
                                              unsigned short* __restrict__ zout,
                                              int n) {
    int gid = blockIdx.x * 256 + threadIdx.x;
    int j = gid >> 4, lane = gid & 15;
    if (j >= n) return;
    int b = rp[j], e = rp[j + 1];
    float s0[8], s1[8];
#pragma unroll
    for (int q = 0; q < 8; ++q) { s0[q] = 0.f; s1[q] = 0.f; }
    int k = b;
    for (; k + 1 < e; k += 2) {
        bf16x8 v0 = *(const bf16x8*)&xb[(size_t)csr[k]     * 128 + lane * 8];
        bf16x8 v1 = *(const bf16x8*)&xb[(size_t)csr[k + 1] * 128 + lane * 8];
#pragma unroll
        for (int q = 0; q < 8; ++q) { s0[q] += (float)v0[q]; s1[q] += (float)v1[q]; }
    }
    if (k < e) {
        bf16x8 v0 = *(const bf16x8*)&xb[(size_t)csr[k] * 128 + lane * 8];
#pragma unroll
        for (int q = 0; q < 8; ++q) s0[q] += (float)v0[q];
    }
    const float epsv = 1.0f + epsp[0];
    bf16x8 xv = *(const bf16x8*)&xb[(size_t)j * 128 + lane * 8];
    bf16x8 o;
#pragma unroll
    for (int q = 0; q < 8; ++q)
        o[q] = (__bf16)(epsv * (float)xv[q] + s0[q] + s1[q]);
    *(bf16x8*)&zout[(size_t)j * 128 + lane * 8] = o;
}

// ---------------- MLP (layer 0): out = relu( relu(z@w1+b1) @ w2 + b2 ) ----
// BM=128 rows/block, 256 threads = 4 waves (2x2 of 64x64); 34.8 KB LDS;
// B from global (L2-resident); output via LDS -> bf16x8 full-line stores.
__global__ __launch_bounds__(256) void k_mlp(const unsigned short* __restrict__ zbuf,
                                             const unsigned short* __restrict__ w1T,
                                             const float* __restrict__ b1,
                                             const unsigned short* __restrict__ w2T,
                                             const float* __restrict__ b2,
                                             unsigned short* __restrict__ out,
                                             int nrows) {
    __shared__ unsigned short zt[128 * LDR];   // 34.8 KB
    const int t = threadIdx.x;
    const int row0 = blockIdx.x * 128;
    if (row0 >= nrows) return;

    for (int i = t; i < 2048; i += 256) {
        int r = i >> 4, c = i & 15;
        int g = row0 + r;
        bf16x8 zv;
        if (g < nrows) {
            zv = *(const bf16x8*)&zbuf[(size_t)g * 128 + c * 8];
        } else {
#pragma unroll
            for (int q = 0; q < 8; ++q) zv[q] = (__bf16)0.0f;
        }
        *(bf16x8*)&zt[r * LDR + c * 8] = zv;
    }
    __syncthreads();

    const int lane = t & 63;
    const int wm = (t >> 7) & 1, wn = (t >> 6) & 1;
    const int lr = lane & 15, lk = lane >> 4;

    f32x4 zero4 = {0.f, 0.f, 0.f, 0.f};
    f32x4 acc[4][4];
#pragma unroll
    for (int mt = 0; mt < 4; ++mt)
#pragma unroll
        for (int nt = 0; nt < 4; ++nt) acc[mt][nt] = zero4;

#pragma unroll
    for (int kb = 0; kb < 4; ++kb) {
        const int c = kb * 4 + lk;
        bf16x8 a[4];
#pragma unroll
        for (int mt = 0; mt < 4; ++mt)
            a[mt] = *(const bf16x8*)&zt[(wm * 64 + mt * 16 + lr) * LDR + c * 8];
#pragma unroll
        for (int nt = 0; nt < 4; ++nt) {
            bf16x8 b = *(const bf16x8*)&w1T[(wn * 64 + nt * 16 + lr) * 128 + c * 8];
#pragma unroll
            for (int mt = 0; mt < 4; ++mt)
                acc[mt][nt] = __builtin_amdgcn_mfma_f32_16x16x32_bf16(a[mt], b, acc[mt][nt], 0, 0, 0);
        }
    }
    __syncthreads();

    // h = relu(acc + b1) -> zt (in place)
#pragma unroll
    for (int nt = 0; nt < 4; ++nt) {
        int col = wn * 64 + nt * 16 + lr;
        float bv = b1[col];
#pragma unroll
        for (int mt = 0; mt < 4; ++mt)
#pragma unroll
            for (int q = 0; q < 4; ++q) {
                int hr = wm * 64 + mt * 16 + lk * 4 + q;
                float hv = fmaxf(acc[mt][nt][q] + bv, 0.f);
                *(__bf16*)&zt[hr * LDR + col] = (__bf16)hv;
            }
    }
    __syncthreads();

    f32x4 acc2[4][4];
#pragma unroll
    for (int mt = 0; mt < 4; ++mt)
#pragma unroll
        for (int nt = 0; nt < 4; ++nt) acc2[mt][nt] = zero4;
#pragma unroll
    for (int kb = 0; kb < 4; ++kb) {
        const int c = kb * 4 + lk;
        bf16x8 a[4];
#pragma unroll
        for (int mt = 0; mt < 4; ++mt)
            a[mt] = *(const bf16x8*)&zt[(wm * 64 + mt * 16 + lr) * LDR + c * 8];
#pragma unroll
        for (int nt = 0; nt < 4; ++nt) {
            bf16x8 b = *(const bf16x8*)&w2T[(wn * 64 + nt * 16 + lr) * 128 + c * 8];
#pragma unroll
            for (int mt = 0; mt < 4; ++mt)
                acc2[mt][nt] = __builtin_amdgcn_mfma_f32_16x16x32_bf16(a[mt], b, acc2[mt][nt], 0, 0, 0);
        }
    }
    __syncthreads();

    // out-tile = relu(acc2 + b2) -> zt
#pragma unroll
    for (int nt = 0; nt < 4; ++nt) {
        int col = wn * 64 + nt * 16 + lr;
        float bv = b2[col];
#pragma unroll
        for (int mt = 0; mt < 4; ++mt)
#pragma unroll
            for (int q = 0; q < 4; ++q) {
                int orow = wm * 64 + mt * 16 + lk * 4 + q;
                float ov = fmaxf(acc2[mt][nt][q] + bv, 0.f);
                *(__bf16*)&zt[orow * LDR + col] = (__bf16)ov;
            }
    }
    __syncthreads();

    for (int i = t; i < 2048; i += 256) {
        int r = i >> 4, c = i & 15;
        int g = row0 + r;
        if (g < nrows)
            *(bf16x8*)&out[(size_t)g * 128 + c * 8] =
                *(const bf16x8*)&zt[r * LDR + c * 8];
    }
}

// ---------------- fused gather + MLP (layer 1, active set) ----------------
// Block = 16 rows, 256 threads; gather keeps segz mapping (16 lanes/row);
// then 4 waves x 16x32 output slice x 2 GEMMs, B from L2-resident weights.
__global__ __launch_bounds__(256, 6) void k_gmlp(const unsigned short* __restrict__ xb,
                                                 const int* __restrict__ rp,
                                                 const int* __restrict__ csr,
                                                 const float* __restrict__ epsp,
                                                 const unsigned short* __restrict__ w1T,
                                                 const float* __restrict__ b1,
                                                 const unsigned short* __restrict__ w2T,
                                                 const float* __restrict__ b2,
                                                 unsigned short* __restrict__ out,
                                                 const int* __restrict__ list,
                                                 const int* __restrict__ cntp, int nrows) {
    __shared__ unsigned short zt[16 * LDR];
    __shared__ unsigned short ht[16 * LDR];
    const int t = threadIdx.x;
    int rows = nrows;
    if (cntp) { int c = *cntp; rows = c < nrows ? c : nrows; }
    const int row0 = blockIdx.x * 16;
    if (row0 >= rows) return;

    {
        const int r16 = t >> 4, lane16 = t & 15;
        int j = row0 + r16;
        bf16x8 zv;
        if (j < rows) {
            int node = list ? list[j] : j;
            int b = rp[node], e = rp[node + 1];
            float s[8];
#pragma unroll
            for (int q = 0; q < 8; ++q) s[q] = 0.f;
            int k = b;
            for (; k + 1 < e; k += 2) {
                bf16x8 v0 = *(const bf16x8*)&xb[(size_t)csr[k]     * 128 + lane16 * 8];
                bf16x8 v1 = *(const bf16x8*)&xb[(size_t)csr[k + 1] * 128 + lane16 * 8];
#pragma unroll
                for (int q = 0; q < 8; ++q) s[q] += (float)v0[q] + (float)v1[q];
            }
            if (k < e) {
                bf16x8 v0 = *(const bf16x8*)&xb[(size_t)csr[k] * 128 + lane16 * 8];
#pragma unroll
                for (int q = 0; q < 8; ++q) s[q] += (float)v0[q];
            }
            const float epsv = 1.0f + epsp[0];
            bf16x8 xv = *(const bf16x8*)&xb[(size_t)node * 128 + lane16 * 8];
#pragma unroll
            for (int q = 0; q < 8; ++q)
                zv[q] = (__bf16)(epsv * (float)xv[q] + s[q]);
        } else {
#pragma unroll
            for (int q = 0; q < 8; ++q) zv[q] = (__bf16)0.0f;
        }
        *(bf16x8*)&zt[(t >> 4) * LDR + (t & 15) * 8] = zv;
    }
    __syncthreads();

    const int lane = t & 63;
    const int wave = t >> 6;
    const int lr = lane & 15, lk = lane >> 4;
    const int n0 = wave * 32;

    f32x4 zero4 = {0.f, 0.f, 0.f, 0.f};
    f32x4 acc[2] = {zero4, zero4};
#pragma unroll
    for (int kb = 0; kb < 4; ++kb) {
        bf16x8 a = *(const bf16x8*)&zt[lr * LDR + (kb * 4 + lk) * 8];
#pragma unroll
        for (int nt = 0; nt < 2; ++nt) {
            bf16x8 b = *(const bf16x8*)&w1T[(size_t)(n0 + nt * 16 + lr) * 128 + (kb * 4 + lk) * 8];
            acc[nt] = __builtin_amdgcn_mfma_f32_16x16x32_bf16(a, b, acc[nt], 0, 0, 0);
        }
    }
#pragma unroll
    for (int nt = 0; nt < 2; ++nt) {
        int col = n0 + nt * 16 + lr;
        float bv = b1[col];
#pragma unroll
        for (int q = 0; q < 4; ++q) {
            float hv = fmaxf(acc[nt][q] + bv, 0.f);
            *(__bf16*)&ht[(lk * 4 + q) * LDR + col] = (__bf16)hv;
        }
    }
    __syncthreads();

    f32x4 acc2[2] = {zero4, zero4};
#pragma unroll
    for (int kb = 0; kb < 4; ++kb) {
        bf16x8 a = *(const bf16x8*)&ht[lr * LDR + (kb * 4 + lk) * 8];
#pragma unroll
        for (int nt = 0; nt < 2; ++nt) {
            bf16x8 b = *(const bf16x8*)&w2T[(size_t)(n0 + nt * 16 + lr) * 128 + (kb * 4 + lk) * 8];
            acc2[nt] = __builtin_amdgcn_mfma_f32_16x16x32_bf16(a, b, acc2[nt], 0, 0, 0);
        }
    }
#pragma unroll
    for (int nt = 0; nt < 2; ++nt) {
        int col = n0 + nt * 16 + lr;
        float bv = b2[col];
#pragma unroll
        for (int q = 0; q < 4; ++q) {
            float ov = fmaxf(acc2[nt][q] + bv, 0.f);
            *(__bf16*)&zt[(lk * 4 + q) * LDR + col] = (__bf16)ov;
        }
    }
    __syncthreads();

    {
        int r = t >> 4, c = t & 15;
        int g = row0 + r;
        if (g < rows) {
            int node = list ? list[g] : g;
            *(bf16x8*)&out[(size_t)node * 128 + c * 8] =
                *(const bf16x8*)&zt[r * LDR + c * 8];
        }
    }
}

// ---------------- layer 2 at roots only ----------------
__global__ __launch_bounds__(128) void k_root(const unsigned short* __restrict__ x2,
                                              const int* __restrict__ rp,
                                              const int* __restrict__ csr,
                                              const int* __restrict__ roots,
                                              const float* __restrict__ epsp,
                                              const float* __restrict__ wa,
                                              const float* __restrict__ ba,
                                              const float* __restrict__ wb,
                                              const float* __restrict__ bb,
                                              float* __restrict__ out) {
    __shared__ float hin[128];
    __shared__ float h[64];
    int r = blockIdx.x, t = threadIdx.x;
    int node = roots[r];
    float s = (1.0f + epsp[0]) * (float)(*(const __bf16*)&x2[(size_t)node * 128 + t]);
    int b = rp[node], e = rp[node + 1];
    for (int k = b; k < e; ++k)
        s += (float)(*(const __bf16*)&x2[(size_t)csr[k] * 128 + t]);
    hin[t] = s;
    __syncthreads();
    if (t < 64) {
        float a = ba[t];
        for (int k = 0; k < 128; ++k) a += hin[k] * wa[k * 64 + t];
        h[t] = fmaxf(a, 0.f);
    }
    __syncthreads();
    if (t < 64) {
        float a = bb[t];
        for (int k = 0; k < 64; ++k) a += h[k] * wb[k * 64 + t];
        out[(size_t)r * 64 + t] = a;
    }
}

extern "C" void kernel_launch(void* const* d_in, const int* in_sizes, int n_in,
                              void* d_out, int out_size, void* d_ws, size_t ws_size,
                              hipStream_t stream) {
    const float* x    = (const float*)d_in[0];
    const int*   ei   = (const int*)d_in[1];
    const int*   root = (const int*)d_in[2];
    const float* eps0 = (const float*)d_in[3];
    const float* w0a  = (const float*)d_in[4];
    const float* b0a  = (const float*)d_in[5];
    const float* w0b  = (const float*)d_in[6];
    const float* b0b  = (const float*)d_in[7];
    const float* eps1 = (const float*)d_in[8];
    const float* w1a  = (const float*)d_in[9];
    const float* b1a  = (const float*)d_in[10];
    const float* w1b  = (const float*)d_in[11];
    const float* b1b  = (const float*)d_in[12];
    const float* eps2 = (const float*)d_in[13];
    const float* w2a  = (const float*)d_in[14];
    const float* b2a  = (const float*)d_in[15];
    const float* w2b  = (const float*)d_in[16];
    const float* b2b  = (const float*)d_in[17];

    const int N  = in_sizes[0] / 128;
    const int E  = in_sizes[1] / 2;
    const int NR = in_sizes[2];
    const int MAXACT = 65536;
    const int NB = (N + 127) / 128;           // buckets of 128 nodes (782)
    const int* src = ei;
    const int* dst = ei + E;

    // ---- workspace layout ----
    char* p = (char*)d_ws;
    unsigned short* xb = (unsigned short*)p; p += (size_t)N * 128 * 2;        // 25.6 MB
    unsigned short* x1 = (unsigned short*)p; p += (size_t)N * 128 * 2;        // 25.6 MB
    unsigned short* z0 = (unsigned short*)p; p += (size_t)N * 128 * 2;        // 25.6 MB
    // shared region: ebuf (CSR build) then x2 (layer-1 output) — disjoint
    char* shared0 = p;
    size_t ebuf_bytes = (size_t)NB * CAP * 4;                                 // 25.6 MB
    size_t x2_bytes   = (size_t)N * 128 * 2;                                  // 25.6 MB
    p += (ebuf_bytes > x2_bytes ? ebuf_bytes : x2_bytes);
    unsigned*       ebuf = (unsigned*)shared0;
    unsigned short* x2   = (unsigned short*)shared0;
    unsigned short* wT   = (unsigned short*)p; p += 4 * 128 * 128 * 2;
    int* rp      = (int*)p; p += (size_t)(N + 64) * 4;
    int* list    = (int*)p; p += (size_t)(N + 64) * 4;
    int* boff    = (int*)p; p += 4096;
    // zeroed region (single memset): af | af_root | cnt | gcnt | realcnt
    char* zbeg = p;
    int* af      = (int*)p; p += (size_t)(N + 64) * 4;
    int* af_root = (int*)p; p += (size_t)(N + 64) * 4;
    int* cnt     = (int*)p; p += 256;
    int* gcnt    = (int*)p; p += (size_t)NB * 16 * 4;      // 64B-padded counters
    int* realcnt = (int*)p; p += (size_t)(NB + 64) * 4;
    size_t zbytes = (size_t)(p - zbeg);
    int* csr     = (int*)p; p += (size_t)E * 4;
    unsigned short* w0aT = wT;
    unsigned short* w0bT = wT + 16384;
    unsigned short* w1aT = wT + 32768;
    unsigned short* w1bT = wT + 49152;

    // ---- CSR build + conversions (merged) ----
    hipMemsetAsync(zbeg, 0, zbytes, stream);
    k_scatter<<<256, 1024, 0, stream>>>(src, dst, gcnt, realcnt, ebuf, E, NB,
                                        (const float4*)x, xb, (long)N * 16,
                                        w0a, w0b, w1a, w1b, wT,
                                        root, NR, af_root);
    k_bscan<<<1, 1024, 0, stream>>>(realcnt, boff, rp, NB, N, E);
    k_build<<<NB, 512, 0, stream>>>(ebuf, gcnt, boff, rp, csr, af_root, af, N);
    k_compact<<<(N + 255) / 256, 256, 0, stream>>>(af, list, cnt, N);

    // ---- layer 0 (all nodes): separate max-TLP gather + 128-row MFMA MLP ----
    k_segz<<<(N * 16 + 255) / 256, 256, 0, stream>>>(xb, rp, csr, eps0, z0, N);
    k_mlp<<<(N + 127) / 128, 256, 0, stream>>>(z0, w0aT, b0a, w0bT, b0b, x1, N);
    // ---- layer 1 (active set only): fused gather+MLP ----
    k_gmlp<<<(MAXACT + 15) / 16, 256, 0, stream>>>(x1, rp, csr, eps1,
                                                   w1aT, b1a, w1bT, b1b,
                                                   x2, list, cnt, MAXACT);
    // ---- layer 2 (roots only) ----
    k_root<<<NR, 128, 0, stream>>>(x2, rp, csr, root, eps2, w2a, b2a, w2b, b2b,
                                   (float*)d_out);
}

// Round 17
// 194.428 us; speedup vs baseline: 1.6561x; 1.0453x over previous
//
#include <hip/hip_runtime.h>

// ---------------------------------------------------------------------------
// GIN 3-layer forward on MI355X (gfx950).
//   - features/weights bf16 node-major (f32 accumulate). Node-major 256B rows
//     gather at ~7.2 TB/s L2-miss fabric traffic = the 8-XCD fabric ceiling
//     (R12-R16: 62us invariant across 5 structural variants; re-layout and
//     fusion attempts all regressed).
//   - k_scatter (merged): LDS-binned edge scatter with FULL-LINE flushes
//     (sentinel-padded 64B bursts; this chip's L2 does NOT merge scattered
//     partial-line stores) + x f32->bf16 conversion + weight transpose +
//     root bitmap, all hidden under the latency-bound binning.
//   - k_build (merged): per-bucket histogram -> scan -> rp -> csr slotting,
//     flags root in-neighbors inline (af) via af_root bitmap.
//   - k_segz (R17): max-TLP gather, 4-edge unroll (4 outstanding row loads
//     per lane), hoisted self-row load; tail blocks of the SAME launch run
//     the active-set compaction (one fewer dispatch).
//   - k_mlp: MFMA 16x16x32 bf16, BM=128, 4 waves, 34.8 KB LDS; B from global
//     (L2-resident); output via LDS -> bf16x8 full-line stores.
//   - k_gmlp (layer 1, 17K rows): fused gather+MLP (imbalance tax < launch
//     + z-roundtrip saved at this size; R15/R16 measured).
//   - layer 2 only at the 1024 roots.
//   NOTE: edge packing assumes N <= 2^17; bins assume N <= 100352.
// ---------------------------------------------------------------------------

typedef __bf16  bf16x8 __attribute__((ext_vector_type(8)));
typedef float   f32x4  __attribute__((ext_vector_type(4)));

#define NBINS 784     // >= (N+127)/128
#define BCAP  38      // words per LDS bin (per-bin lambda ~8)
#define CAP   8192    // words per global bucket cell (real ~2048 + pads)
#define LDR   136     // LDS row stride in shorts (+8 pad)

// ---------------- merged scatter + conversions + root flag ----------------
__global__ __launch_bounds__(1024) void k_scatter(const int* __restrict__ src,
                                                  const int* __restrict__ dst,
                                                  int* __restrict__ gcnt,     // NB*16 padded
                                                  int* __restrict__ realcnt,  // NB
                                                  unsigned* __restrict__ ebuf,
                                                  int e, int nb,
                                                  const float4* __restrict__ xf,
                                                  unsigned short* __restrict__ xb,
                                                  long n8,
                                                  const float* __restrict__ w0a,
                                                  const float* __restrict__ w0b,
                                                  const float* __restrict__ w1a,
                                                  const float* __restrict__ w1b,
                                                  unsigned short* __restrict__ wT,
                                                  const int* __restrict__ roots,
                                                  int nr,
                                                  int* __restrict__ af_root) {
    __shared__ unsigned lbuf[NBINS * BCAP];   // 119.2 KB
    __shared__ int lcnt[NBINS];
    __shared__ int sbase[NBINS];
    const int t = threadIdx.x;
    for (int b = t; b < nb; b += 1024) lcnt[b] = 0;

    {
        int gi = blockIdx.x * 1024 + t;
        if (gi < nr) af_root[roots[gi]] = 1;
    }
    {
        int gi = blockIdx.x * 1024 + t;
        if (gi < 65536) {
            int m = gi >> 14, j = gi & 16383;
            const float* w = (m == 0) ? w0a : (m == 1) ? w0b : (m == 2) ? w1a : w1b;
            int k = j >> 7, n = j & 127;
            *(__bf16*)&wT[m * 16384 + n * 128 + k] = (__bf16)w[j];
        }
    }
    for (long i = (long)blockIdx.x * 1024 + t; i < n8; i += 262144) {
        float4 a = xf[2 * i], b = xf[2 * i + 1];
        bf16x8 v;
        v[0] = (__bf16)a.x; v[1] = (__bf16)a.y; v[2] = (__bf16)a.z; v[3] = (__bf16)a.w;
        v[4] = (__bf16)b.x; v[5] = (__bf16)b.y; v[6] = (__bf16)b.z; v[7] = (__bf16)b.w;
        *(bf16x8*)&xb[i * 8] = v;
    }
    __syncthreads();

    const int per = (((e + 255) / 256) + 7) & ~7;   // 8-aligned slice, 256 blocks
    const int beg = blockIdx.x * per;
    const int end = (beg + per < e) ? beg + per : e;

    for (int base = beg; base < end; base += 8192) {
        int i0 = base + t * 8;
        if (i0 >= end) continue;
        if (i0 + 8 <= end) {
            int4 s0 = *(const int4*)&src[i0];
            int4 s1 = *(const int4*)&src[i0 + 4];
            int4 d0 = *(const int4*)&dst[i0];
            int4 d1 = *(const int4*)&dst[i0 + 4];
            int ss[8] = {s0.x, s0.y, s0.z, s0.w, s1.x, s1.y, s1.z, s1.w};
            int dd[8] = {d0.x, d0.y, d0.z, d0.w, d1.x, d1.y, d1.z, d1.w};
#pragma unroll
            for (int q = 0; q < 8; ++q) {
                int b = dd[q] >> 7;
                int p = atomicAdd(&lcnt[b], 1);
                if (p < BCAP)
                    lbuf[b * BCAP + p] =
                        (unsigned)ss[q] | ((unsigned)(dd[q] & 127) << 17);
            }
        } else {
            int lim = (i0 + 8 < end) ? i0 + 8 : end;
            for (int i = i0; i < lim; ++i) {
                int d = dst[i];
                int b = d >> 7;
                int p = atomicAdd(&lcnt[b], 1);
                if (p < BCAP)
                    lbuf[b * BCAP + p] =
                        (unsigned)src[i] | ((unsigned)(d & 127) << 17);
            }
        }
    }
    __syncthreads();

    for (int b = t; b < nb; b += 1024) {
        int r = lcnt[b]; if (r > BCAP) r = BCAP;
        int bb = 0;
        if (r > 0) {
            int nf = (r + 15) & ~15;
            bb = atomicAdd(&gcnt[b * 16], nf);
            atomicAdd(&realcnt[b], r);
        }
        sbase[b] = bb;
    }
    __syncthreads();

    const int wave = t >> 6, lane = t & 63;
    const int gidx = wave * 4 + (lane >> 4), sub = lane & 15;
    for (int b = gidx; b < nb; b += 64) {
        int r = lcnt[b]; if (r > BCAP) r = BCAP;
        if (r == 0) continue;
        int nf = (r + 15) & ~15;
        int base2 = sbase[b];
        unsigned* cell = ebuf + (size_t)b * CAP;
        for (int j = sub; j < nf; j += 16) {
            unsigned v = (j < r) ? lbuf[b * BCAP + j] : 0xFFFFFFFFu;
            if (base2 + j < CAP) cell[base2 + j] = v;
        }
    }
}

__global__ __launch_bounds__(1024) void k_bscan(const int* __restrict__ realcnt,
                                                int* __restrict__ boff,
                                                int* __restrict__ rp,
                                                int nb, int n, int e) {
    __shared__ int sh[1024];
    int t = threadIdx.x;
    sh[t] = (t < nb) ? realcnt[t] : 0;
    __syncthreads();
    for (int off = 1; off < 1024; off <<= 1) {
        int u = (t >= off) ? sh[t - off] : 0;
        __syncthreads();
        sh[t] += u;
        __syncthreads();
    }
    if (t < nb) boff[t] = (t == 0) ? 0 : sh[t - 1];
    if (t == 0) rp[n] = e;
}

__global__ __launch_bounds__(512) void k_build(const unsigned* __restrict__ ebuf,
                                               const int* __restrict__ gcnt,
                                               const int* __restrict__ boff,
                                               int* __restrict__ rp,
                                               int* __restrict__ csr,
                                               const int* __restrict__ af_root,
                                               int* __restrict__ af, int n) {
    __shared__ int bins[128];
    __shared__ int incl[128];
    __shared__ int cur[128];
    __shared__ unsigned char isroot[128];
    int b = blockIdx.x, t = threadIdx.x;
    if (t < 128) {
        bins[t] = 0;
        int node = b * 128 + t;
        unsigned char ir = (node < n && af_root[node]) ? 1 : 0;
        isroot[t] = ir;
        if (ir) af[node] = 1;
    }
    __syncthreads();
    int c = gcnt[b * 16]; if (c > CAP) c = CAP;
    const unsigned* seg = ebuf + ((size_t)b * CAP);
    for (int j = t; j < c; j += 512) {
        unsigned w = seg[j];
        if (w != 0xFFFFFFFFu) atomicAdd(&bins[(w >> 17) & 127], 1);
    }
    __syncthreads();
    if (t < 128) incl[t] = bins[t];
    __syncthreads();
    for (int off = 1; off < 128; off <<= 1) {
        int u = (t < 128 && t >= off) ? incl[t - off] : 0;
        __syncthreads();
        if (t < 128) incl[t] += u;
        __syncthreads();
    }
    int base = boff[b];
    if (t < 128) {
        int ex = (t == 0) ? 0 : incl[t - 1];
        cur[t] = ex;
        int node = b * 128 + t;
        if (node < n) rp[node] = base + ex;
    }
    __syncthreads();
    for (int j = t; j < c; j += 512) {
        unsigned w = seg[j];
        if (w != 0xFFFFFFFFu) {
            int ldst = (w >> 17) & 127;
            int s = (int)(w & 0x1FFFF);
            int slot = atomicAdd(&cur[ldst], 1);
            csr[base + slot] = s;
            if (isroot[ldst]) af[s] = 1;
        }
    }
}

// ---------------- gather + GIN update (layer 0) + tail-block compaction ----
// Blocks [0, nsegb): z[j] = (1+eps)*x[j] + sum_{s in N(j)} x[s]; 16 lanes/row,
// 4-edge unroll (4 outstanding 16B row loads/lane), hoisted self-row load.
// Blocks [nsegb, ...): active-set compaction (af -> list, cnt).
__global__ __launch_bounds__(256) void k_segz(const unsigned short* __restrict__ xb,
                                              const int* __restrict__ rp,
                                              const int* __restrict__ csr,
                                              const float* __restrict__ epsp,
                                              unsigned short* __restrict__ zout,
                                              int n, int nsegb,
                                              const int* __restrict__ af,
                                              int* __restrict__ list,
                                              int* __restrict__ cnt) {
    if ((int)blockIdx.x >= nsegb) {
        int i = (blockIdx.x - nsegb) * 256 + threadIdx.x;
        if (i < n && af[i]) {
            int p = atomicAdd(cnt, 1);
            list[p] = i;
        }
        return;
    }
    int gid = blockIdx.x * 256 + threadIdx.x;
    int j = gid >> 4, lane = gid & 15;
    if (j >= n) return;
    int b = rp[j], e = rp[j + 1];
    bf16x8 xv = *(const bf16x8*)&xb[(size_t)j * 128 + lane * 8];   // hoisted
    float s0[8], s1[8];
#pragma unroll
    for (int q = 0; q < 8; ++q) { s0[q] = 0.f; s1[q] = 0.f; }
    int k = b;
    for (; k + 3 < e; k += 4) {
        int c0 = csr[k], c1 = csr[k + 1], c2 = csr[k + 2], c3 = csr[k + 3];
        bf16x8 v0 = *(const bf16x8*)&xb[(size_t)c0 * 128 + lane * 8];
        bf16x8 v1 = *(const bf16x8*)&xb[(size_t)c1 * 128 + lane * 8];
        bf16x8 v2 = *(const bf16x8*)&xb[(size_t)c2 * 128 + lane * 8];
        bf16x8 v3 = *(const bf16x8*)&xb[(size_t)c3 * 128 + lane * 8];
#pragma unroll
        for (int q = 0; q < 8; ++q) {
            s0[q] += (float)v0[q] + (float)v2[q];
            s1[q] += (float)v1[q] + (float)v3[q];
        }
    }
    for (; k < e; ++k) {
        bf16x8 v0 = *(const bf16x8*)&xb[(size_t)csr[k] * 128 + lane * 8];
#pragma unroll
        for (int q = 0; q < 8; ++q) s0[q] += (float)v0[q];
    }
    const float epsv = 1.0f + epsp[0];
    bf16x8 o;
#pragma unroll
    for (int q = 0; q < 8; ++q)
        o[q] = (__bf16)(epsv * (float)xv[q] + s0[q] + s1[q]);
    *(bf16x8*)&zout[(size_t)j * 128 + lane * 8] = o;
}

// ---------------- MLP (layer 0): out = relu( relu(z@w1+b1) @ w2 + b2 ) ----
__global__ __launch_bounds__(256) void k_mlp(const unsigned short* __restrict__ zbuf,
                                             const unsigned short* __restrict__ w1T,
                                             const float* __restrict__ b1,
                                             const unsigned short* __restrict__ w2T,
                                             const float* __restrict__ b2,
                                             unsigned short* __restrict__ out,
                                             int nrows) {
    __shared__ unsigned short zt[128 * LDR];   // 34.8 KB
    const int t = threadIdx.x;
    const int row0 = blockIdx.x * 128;
    if (row0 >= nrows) return;

    for (int i = t; i < 2048; i += 256) {
        int r = i >> 4, c = i & 15;
        int g = row0 + r;
        bf16x8 zv;
        if (g < nrows) {
            zv = *(const bf16x8*)&zbuf[(size_t)g * 128 + c * 8];
        } else {
#pragma unroll
            for (int q = 0; q < 8; ++q) zv[q] = (__bf16)0.0f;
        }
        *(bf16x8*)&zt[r * LDR + c * 8] = zv;
    }
    __syncthreads();

    const int lane = t & 63;
    const int wm = (t >> 7) & 1, wn = (t >> 6) & 1;
    const int lr = lane & 15, lk = lane >> 4;

    f32x4 zero4 = {0.f, 0.f, 0.f, 0.f};
    f32x4 acc[4][4];
#pragma unroll
    for (int mt = 0; mt < 4; ++mt)
#pragma unroll
        for (int nt = 0; nt < 4; ++nt) acc[mt][nt] = zero4;

#pragma unroll
    for (int kb = 0; kb < 4; ++kb) {
        const int c = kb * 4 + lk;
        bf16x8 a[4];
#pragma unroll
        for (int mt = 0; mt < 4; ++mt)
            a[mt] = *(const bf16x8*)&zt[(wm * 64 + mt * 16 + lr) * LDR + c * 8];
#pragma unroll
        for (int nt = 0; nt < 4; ++nt) {
            bf16x8 b = *(const bf16x8*)&w1T[(wn * 64 + nt * 16 + lr) * 128 + c * 8];
#pragma unroll
            for (int mt = 0; mt < 4; ++mt)
                acc[mt][nt] = __builtin_amdgcn_mfma_f32_16x16x32_bf16(a[mt], b, acc[mt][nt], 0, 0, 0);
        }
    }
    __syncthreads();

    // h = relu(acc + b1) -> zt (in place)
#pragma unroll
    for (int nt = 0; nt < 4; ++nt) {
        int col = wn * 64 + nt * 16 + lr;
        float bv = b1[col];
#pragma unroll
        for (int mt = 0; mt < 4; ++mt)
#pragma unroll
            for (int q = 0; q < 4; ++q) {
                int hr = wm * 64 + mt * 16 + lk * 4 + q;
                float hv = fmaxf(acc[mt][nt][q] + bv, 0.f);
                *(__bf16*)&zt[hr * LDR + col] = (__bf16)hv;
            }
    }
    __syncthreads();

    f32x4 acc2[4][4];
#pragma unroll
    for (int mt = 0; mt < 4; ++mt)
#pragma unroll
        for (int nt = 0; nt < 4; ++nt) acc2[mt][nt] = zero4;
#pragma unroll
    for (int kb = 0; kb < 4; ++kb) {
        const int c = kb * 4 + lk;
        bf16x8 a[4];
#pragma unroll
        for (int mt = 0; mt < 4; ++mt)
            a[mt] = *(const bf16x8*)&zt[(wm * 64 + mt * 16 + lr) * LDR + c * 8];
#pragma unroll
        for (int nt = 0; nt < 4; ++nt) {
            bf16x8 b = *(const bf16x8*)&w2T[(wn * 64 + nt * 16 + lr) * 128 + c * 8];
#pragma unroll
            for (int mt = 0; mt < 4; ++mt)
                acc2[mt][nt] = __builtin_amdgcn_mfma_f32_16x16x32_bf16(a[mt], b, acc2[mt][nt], 0, 0, 0);
        }
    }
    __syncthreads();

#pragma unroll
    for (int nt = 0; nt < 4; ++nt) {
        int col = wn * 64 + nt * 16 + lr;
        float bv = b2[col];
#pragma unroll
        for (int mt = 0; mt < 4; ++mt)
#pragma unroll
            for (int q = 0; q < 4; ++q) {
                int orow = wm * 64 + mt * 16 + lk * 4 + q;
                float ov = fmaxf(acc2[mt][nt][q] + bv, 0.f);
                *(__bf16*)&zt[orow * LDR + col] = (__bf16)ov;
            }
    }
    __syncthreads();

    for (int i = t; i < 2048; i += 256) {
        int r = i >> 4, c = i & 15;
        int g = row0 + r;
        if (g < nrows)
            *(bf16x8*)&out[(size_t)g * 128 + c * 8] =
                *(const bf16x8*)&zt[r * LDR + c * 8];
    }
}

// ---------------- fused gather + MLP (layer 1, active set) ----------------
__global__ __launch_bounds__(256, 6) void k_gmlp(const unsigned short* __restrict__ xb,
                                                 const int* __restrict__ rp,
                                                 const int* __restrict__ csr,
                                                 const float* __restrict__ epsp,
                                                 const unsigned short* __restrict__ w1T,
                                                 const float* __restrict__ b1,
                                                 const unsigned short* __restrict__ w2T,
                                                 const float* __restrict__ b2,
                                                 unsigned short* __restrict__ out,
                                                 const int* __restrict__ list,
                                                 const int* __restrict__ cntp, int nrows) {
    __shared__ unsigned short zt[16 * LDR];
    __shared__ unsigned short ht[16 * LDR];
    const int t = threadIdx.x;
    int rows = nrows;
    if (cntp) { int c = *cntp; rows = c < nrows ? c : nrows; }
    const int row0 = blockIdx.x * 16;
    if (row0 >= rows) return;

    {
        const int r16 = t >> 4, lane16 = t & 15;
        int j = row0 + r16;
        bf16x8 zv;
        if (j < rows) {
            int node = list ? list[j] : j;
            int b = rp[node], e = rp[node + 1];
            bf16x8 xv = *(const bf16x8*)&xb[(size_t)node * 128 + lane16 * 8];
            float s0[8], s1[8];
#pragma unroll
            for (int q = 0; q < 8; ++q) { s0[q] = 0.f; s1[q] = 0.f; }
            int k = b;
            for (; k + 3 < e; k += 4) {
                int c0 = csr[k], c1 = csr[k + 1], c2 = csr[k + 2], c3 = csr[k + 3];
                bf16x8 v0 = *(const bf16x8*)&xb[(size_t)c0 * 128 + lane16 * 8];
                bf16x8 v1 = *(const bf16x8*)&xb[(size_t)c1 * 128 + lane16 * 8];
                bf16x8 v2 = *(const bf16x8*)&xb[(size_t)c2 * 128 + lane16 * 8];
                bf16x8 v3 = *(const bf16x8*)&xb[(size_t)c3 * 128 + lane16 * 8];
#pragma unroll
                for (int q = 0; q < 8; ++q) {
                    s0[q] += (float)v0[q] + (float)v2[q];
                    s1[q] += (float)v1[q] + (float)v3[q];
                }
            }
            for (; k < e; ++k) {
                bf16x8 v0 = *(const bf16x8*)&xb[(size_t)csr[k] * 128 + lane16 * 8];
#pragma unroll
                for (int q = 0; q < 8; ++q) s0[q] += (float)v0[q];
            }
            const float epsv = 1.0f + epsp[0];
#pragma unroll
            for (int q = 0; q < 8; ++q)
                zv[q] = (__bf16)(epsv * (float)xv[q] + s0[q] + s1[q]);
        } else {
#pragma unroll
            for (int q = 0; q < 8; ++q) zv[q] = (__bf16)0.0f;
        }
        *(bf16x8*)&zt[(t >> 4) * LDR + (t & 15) * 8] = zv;
    }
    __syncthreads();

    const int lane = t & 63;
    const int wave = t >> 6;
    const int lr = lane & 15, lk = lane >> 4;
    const int n0 = wave * 32;

    f32x4 zero4 = {0.f, 0.f, 0.f, 0.f};
    f32x4 acc[2] = {zero4, zero4};
#pragma unroll
    for (int kb = 0; kb < 4; ++kb) {
        bf16x8 a = *(const bf16x8*)&zt[lr * LDR + (kb * 4 + lk) * 8];
#pragma unroll
        for (int nt = 0; nt < 2; ++nt) {
            bf16x8 b = *(const bf16x8*)&w1T[(size_t)(n0 + nt * 16 + lr) * 128 + (kb * 4 + lk) * 8];
            acc[nt] = __builtin_amdgcn_mfma_f32_16x16x32_bf16(a, b, acc[nt], 0, 0, 0);
        }
    }
#pragma unroll
    for (int nt = 0; nt < 2; ++nt) {
        int col = n0 + nt * 16 + lr;
        float bv = b1[col];
#pragma unroll
        for (int q = 0; q < 4; ++q) {
            float hv = fmaxf(acc[nt][q] + bv, 0.f);
            *(__bf16*)&ht[(lk * 4 + q) * LDR + col] = (__bf16)hv;
        }
    }
    __syncthreads();

    f32x4 acc2[2] = {zero4, zero4};
#pragma unroll
    for (int kb = 0; kb < 4; ++kb) {
        bf16x8 a = *(const bf16x8*)&ht[lr * LDR + (kb * 4 + lk) * 8];
#pragma unroll
        for (int nt = 0; nt < 2; ++nt) {
            bf16x8 b = *(const bf16x8*)&w2T[(size_t)(n0 + nt * 16 + lr) * 128 + (kb * 4 + lk) * 8];
            acc2[nt] = __builtin_amdgcn_mfma_f32_16x16x32_bf16(a, b, acc2[nt], 0, 0, 0);
        }
    }
#pragma unroll
    for (int nt = 0; nt < 2; ++nt) {
        int col = n0 + nt * 16 + lr;
        float bv = b2[col];
#pragma unroll
        for (int q = 0; q < 4; ++q) {
            float ov = fmaxf(acc2[nt][q] + bv, 0.f);
            *(__bf16*)&zt[(lk * 4 + q) * LDR + col] = (__bf16)ov;
        }
    }
    __syncthreads();

    {
        int r = t >> 4, c = t & 15;
        int g = row0 + r;
        if (g < rows) {
            int node = list ? list[g] : g;
            *(bf16x8*)&out[(size_t)node * 128 + c * 8] =
                *(const bf16x8*)&zt[r * LDR + c * 8];
        }
    }
}

// ---------------- layer 2 at roots only ----------------
__global__ __launch_bounds__(128) void k_root(const unsigned short* __restrict__ x2,
                                              const int* __restrict__ rp,
                                              const int* __restrict__ csr,
                                              const int* __restrict__ roots,
                                              const float* __restrict__ epsp,
                                              const float* __restrict__ wa,
                                              const float* __restrict__ ba,
                                              const float* __restrict__ wb,
                                              const float* __restrict__ bb,
                                              float* __restrict__ out) {
    __shared__ float hin[128];
    __shared__ float h[64];
    int r = blockIdx.x, t = threadIdx.x;
    int node = roots[r];
    float s = (1.0f + epsp[0]) * (float)(*(const __bf16*)&x2[(size_t)node * 128 + t]);
    int b = rp[node], e = rp[node + 1];
    for (int k = b; k < e; ++k)
        s += (float)(*(const __bf16*)&x2[(size_t)csr[k] * 128 + t]);
    hin[t] = s;
    __syncthreads();
    if (t < 64) {
        float a = ba[t];
        for (int k = 0; k < 128; ++k) a += hin[k] * wa[k * 64 + t];
        h[t] = fmaxf(a, 0.f);
    }
    __syncthreads();
    if (t < 64) {
        float a = bb[t];
        for (int k = 0; k < 64; ++k) a += h[k] * wb[k * 64 + t];
        out[(size_t)r * 64 + t] = a;
    }
}

extern "C" void kernel_launch(void* const* d_in, const int* in_sizes, int n_in,
                              void* d_out, int out_size, void* d_ws, size_t ws_size,
                              hipStream_t stream) {
    const float* x    = (const float*)d_in[0];
    const int*   ei   = (const int*)d_in[1];
    const int*   root = (const int*)d_in[2];
    const float* eps0 = (const float*)d_in[3];
    const float* w0a  = (const float*)d_in[4];
    const float* b0a  = (const float*)d_in[5];
    const float* w0b  = (const float*)d_in[6];
    const float* b0b  = (const float*)d_in[7];
    const float* eps1 = (const float*)d_in[8];
    const float* w1a  = (const float*)d_in[9];
    const float* b1a  = (const float*)d_in[10];
    const float* w1b  = (const float*)d_in[11];
    const float* b1b  = (const float*)d_in[12];
    const float* eps2 = (const float*)d_in[13];
    const float* w2a  = (const float*)d_in[14];
    const float* b2a  = (const float*)d_in[15];
    const float* w2b  = (const float*)d_in[16];
    const float* b2b  = (const float*)d_in[17];

    const int N  = in_sizes[0] / 128;
    const int E  = in_sizes[1] / 2;
    const int NR = in_sizes[2];
    const int MAXACT = 65536;
    const int NB = (N + 127) / 128;           // buckets of 128 nodes (782)
    const int* src = ei;
    const int* dst = ei + E;

    // ---- workspace layout ----
    char* p = (char*)d_ws;
    unsigned short* xb = (unsigned short*)p; p += (size_t)N * 128 * 2;        // 25.6 MB
    unsigned short* x1 = (unsigned short*)p; p += (size_t)N * 128 * 2;        // 25.6 MB
    unsigned short* z0 = (unsigned short*)p; p += (size_t)N * 128 * 2;        // 25.6 MB
    // shared region: ebuf (CSR build) then x2 (layer-1 output) — disjoint
    char* shared0 = p;
    size_t ebuf_bytes = (size_t)NB * CAP * 4;                                 // 25.6 MB
    size_t x2_bytes   = (size_t)N * 128 * 2;                                  // 25.6 MB
    p += (ebuf_bytes > x2_bytes ? ebuf_bytes : x2_bytes);
    unsigned*       ebuf = (unsigned*)shared0;
    unsigned short* x2   = (unsigned short*)shared0;
    unsigned short* wT   = (unsigned short*)p; p += 4 * 128 * 128 * 2;
    int* rp      = (int*)p; p += (size_t)(N + 64) * 4;
    int* list    = (int*)p; p += (size_t)(N + 64) * 4;
    int* boff    = (int*)p; p += 4096;
    // zeroed region (single memset): af | af_root | cnt | gcnt | realcnt
    char* zbeg = p;
    int* af      = (int*)p; p += (size_t)(N + 64) * 4;
    int* af_root = (int*)p; p += (size_t)(N + 64) * 4;
    int* cnt     = (int*)p; p += 256;
    int* gcnt    = (int*)p; p += (size_t)NB * 16 * 4;      // 64B-padded counters
    int* realcnt = (int*)p; p += (size_t)(NB + 64) * 4;
    size_t zbytes = (size_t)(p - zbeg);
    int* csr     = (int*)p; p += (size_t)E * 4;
    unsigned short* w0aT = wT;
    unsigned short* w0bT = wT + 16384;
    unsigned short* w1aT = wT + 32768;
    unsigned short* w1bT = wT + 49152;

    // ---- CSR build + conversions (merged) ----
    hipMemsetAsync(zbeg, 0, zbytes, stream);
    k_scatter<<<256, 1024, 0, stream>>>(src, dst, gcnt, realcnt, ebuf, E, NB,
                                        (const float4*)x, xb, (long)N * 16,
                                        w0a, w0b, w1a, w1b, wT,
                                        root, NR, af_root);
    k_bscan<<<1, 1024, 0, stream>>>(realcnt, boff, rp, NB, N, E);
    k_build<<<NB, 512, 0, stream>>>(ebuf, gcnt, boff, rp, csr, af_root, af, N);

    // ---- layer 0 gather (+ tail-block active-set compaction) ----
    const int segB = (N * 16 + 255) / 256;
    const int cmpB = (N + 255) / 256;
    k_segz<<<segB + cmpB, 256, 0, stream>>>(xb, rp, csr, eps0, z0, N, segB,
                                            af, list, cnt);
    // ---- layer 0 MLP ----
    k_mlp<<<(N + 127) / 128, 256, 0, stream>>>(z0, w0aT, b0a, w0bT, b0b, x1, N);
    // ---- layer 1 (active set only): fused gather+MLP ----
    k_gmlp<<<(MAXACT + 15) / 16, 256, 0, stream>>>(x1, rp, csr, eps1,
                                                   w1aT, b1a, w1bT, b1b,
                                                   x2, list, cnt, MAXACT);
    // ---- layer 2 (roots only) ----
    k_root<<<NR, 128, 0, stream>>>(x2, rp, csr, root, eps2, w2a, b2a, w2b, b2b,
                                   (float*)d_out);
}